// Round 12
// baseline (150.722 us; speedup 1.0000x reference)
//
#include <hip/hip_runtime.h>
#include <hip/hip_bf16.h>
#include <stdint.h>

typedef __attribute__((ext_vector_type(8))) __bf16 bf16x8;
typedef __attribute__((ext_vector_type(4))) float f32x4;
typedef __attribute__((ext_vector_type(16))) float f32x16;
typedef __attribute__((ext_vector_type(8))) unsigned short ushort8;
typedef __attribute__((ext_vector_type(4))) unsigned short ushort4v;
typedef __attribute__((ext_vector_type(2))) unsigned int uint2v;
typedef __attribute__((ext_vector_type(4))) unsigned int uint4v;

__device__ __forceinline__ unsigned short bfbits(float x) {
    __bf16 b = (__bf16)x;
    return __builtin_bit_cast(unsigned short, b);
}
__device__ __forceinline__ float bf2f_u(unsigned short u) {
    return __builtin_bit_cast(float, (unsigned int)u << 16);
}

__device__ __forceinline__ f32x4 mfma16(bf16x8 a, bf16x8 b, f32x4 c) {
    return __builtin_amdgcn_mfma_f32_16x16x32_bf16(a, b, c, 0, 0, 0);
}
__device__ __forceinline__ f32x16 mfma32(bf16x8 a, bf16x8 b, f32x16 c) {
    return __builtin_amdgcn_mfma_f32_32x32x16_bf16(a, b, c, 0, 0, 0);
}

__device__ __forceinline__ unsigned int cvtpk(float lo, float hi) {
    unsigned int r;
    asm("v_cvt_pk_bf16_f32 %0, %1, %2" : "=v"(r) : "v"(lo), "v"(hi));
    return r;
}

// convert two f32x4 (8 consecutive fp32) to one bf16x8 fragment
__device__ __forceinline__ bf16x8 cvt8(f32x4 lo, f32x4 hi) {
    uint4v pk = { cvtpk(lo.x, lo.y), cvtpk(lo.z, lo.w),
                  cvtpk(hi.x, hi.y), cvtpk(hi.z, hi.w) };
    return __builtin_bit_cast(bf16x8, pk);
}

__device__ __forceinline__ float lanepull(float src, int srcl) {
    return __builtin_bit_cast(float,
        __builtin_amdgcn_ds_bpermute(srcl * 4, __builtin_bit_cast(int, src)));
}

__device__ __forceinline__ void gload16(const void* g, void* l) {
    __builtin_amdgcn_global_load_lds(
        (const __attribute__((address_space(1))) unsigned int*)g,
        (__attribute__((address_space(3))) unsigned int*)l, 16, 0, 0);
}

__device__ __forceinline__ f32x16 zero16() {
    f32x16 r;
    #pragma unroll
    for (int i = 0; i < 16; i++) r[i] = 0.f;
    return r;
}

__device__ __forceinline__ int tail_tiles(float tdh, float scale) {
    float cut = 5.3f + __logf(fmaxf(scale, 1e-20f));
    cut = fmaxf(cut, 0.f);
    tdh = fmaxf(tdh, 1e-8f);
    int kt = (int)ceilf(cut / (tdh * 64.f));
    if (kt < 1) kt = 1;
    if (kt > 64) kt = 64;
    return kt;
}

// ---------------------------------------------------------------------------
// Merged Q/K/V projection GEMM (R8-v3 structure; W read directly as fp32,
// converted to bf16 at fragment use — no wconv pass). A fp32 staged via
// global_load_lds into XOR-swizzled dbuf LDS, converted to bf16 at frag
// read; B fp32 fragments prefetched from global (L2) 1 iter ahead.
// 768 blocks XCD-swizzled, 128x128 tile, BK=32, 16 iters, one barrier/iter.
// ---------------------------------------------------------------------------
__global__ __launch_bounds__(256) void gemm_qkv(
    const float* __restrict__ q, const float* __restrict__ k, const float* __restrict__ v,
    const float* __restrict__ Wq, const float* __restrict__ Wk, const float* __restrict__ Wv,
    const float* __restrict__ bq, const float* __restrict__ bk, const float* __restrict__ bv,
    const float* __restrict__ td, const float* __restrict__ sc,
    unsigned short* __restrict__ Qh, unsigned short* __restrict__ Kh,
    unsigned short* __restrict__ Vt)
{
    __shared__ __align__(16) char ALDS[2][16384];   // A tile 128 rows x 128B fp32

    const int id  = blockIdx.x;
    const int nid = (id & 7) * 96 + (id >> 3);
    const int z   = nid >> 8;
    const int rem = nid & 255;
    const int bm  = rem >> 2;
    const int bn  = rem & 3;

    const float* A0   = (z == 0) ? q  : (z == 1) ? k  : v;
    const float* W    = (z == 0) ? Wq : (z == 1) ? Wk : Wv;
    const float* bias = (z == 0) ? bq : (z == 1) ? bk : bv;

    const int tid  = threadIdx.x;
    const int lane = tid & 63;
    const int w    = tid >> 6;
    const int wm   = w >> 1, wn = w & 1;
    const int l15  = lane & 15;
    const int g    = lane >> 4;

    // staging source (pre-swizzled): lane covers row r = w*32 + j*8 + lane>>3
    const int lr  = lane >> 3;
    const int lc  = ((lane & 7) * 16) ^ (lr << 4);
    const char* asrc[4];
    #pragma unroll
    for (int j = 0; j < 4; j++)
        asrc[j] = (const char*)A0 + (size_t)(bm * 128 + w * 32 + j * 8 + lr) * 2048 + lc;
    int adst[4];
    #pragma unroll
    for (int j = 0; j < 4; j++) adst[j] = w * 4096 + j * 1024;

    // B fragment bases (fp32 weights, global; convert at use)
    const float* Bp[4];
    #pragma unroll
    for (int n = 0; n < 4; n++)
        Bp[n] = W + (size_t)(bn * 128 + wn * 64 + n * 16 + l15) * 512 + g * 8;

    f32x4 acc[4][4];
    #pragma unroll
    for (int m = 0; m < 4; m++)
        #pragma unroll
        for (int n = 0; n < 4; n++)
            acc[m][n] = (f32x4){0.f, 0.f, 0.f, 0.f};

    // A-frag read offsets (swizzled)
    const int arow = l15;
    const int asw  = (arow & 7) << 4;

    // prologue: stage kk=0 -> buf0, load B frags kk=0 (fp32)
    #pragma unroll
    for (int j = 0; j < 4; j++) gload16(asrc[j], ALDS[0] + adst[j]);
    f32x4 BA[4][2], BB[4][2];
    #pragma unroll
    for (int n = 0; n < 4; n++) {
        BA[n][0] = *(const f32x4*)Bp[n];
        BA[n][1] = *(const f32x4*)(Bp[n] + 4);
    }

#define QKV_ITER(CUR, KK, BC, BN)                                                  \
    {                                                                              \
        asm volatile("s_waitcnt vmcnt(0)" ::: "memory");                           \
        __syncthreads();                                                           \
        if ((KK) < 15) {                                                           \
            _Pragma("unroll")                                                      \
            for (int j = 0; j < 4; j++)                                            \
                gload16(asrc[j] + (size_t)((KK) + 1) * 128,                        \
                        ALDS[(CUR) ^ 1] + adst[j]);                                \
            _Pragma("unroll")                                                      \
            for (int n = 0; n < 4; n++) {                                          \
                BN[n][0] = *(const f32x4*)(Bp[n] + (size_t)((KK) + 1) * 32);       \
                BN[n][1] = *(const f32x4*)(Bp[n] + (size_t)((KK) + 1) * 32 + 4);   \
            }                                                                      \
        }                                                                          \
        bf16x8 bfr[4];                                                             \
        _Pragma("unroll")                                                          \
        for (int n = 0; n < 4; n++) bfr[n] = cvt8(BC[n][0], BC[n][1]);             \
        bf16x8 af[4];                                                              \
        _Pragma("unroll")                                                          \
        for (int m = 0; m < 4; m++) {                                              \
            const char* base = ALDS[CUR] + (wm * 64 + m * 16 + arow) * 128;        \
            f32x4 v0 = *(const f32x4*)(base + ((g * 32) ^ asw));                   \
            f32x4 v1 = *(const f32x4*)(base + (((g * 32) | 16) ^ asw));            \
            af[m] = cvt8(v0, v1);                                                  \
        }                                                                          \
        __builtin_amdgcn_s_setprio(1);                                             \
        _Pragma("unroll")                                                          \
        for (int m = 0; m < 4; m++)                                                \
            _Pragma("unroll")                                                      \
            for (int n = 0; n < 4; n++)                                            \
                acc[m][n] = mfma16(af[m], bfr[n], acc[m][n]);                      \
        __builtin_amdgcn_s_setprio(0);                                             \
    }

    #pragma unroll 1
    for (int t = 0; t < 8; ++t) {
        QKV_ITER(0, 2 * t, BA, BB)
        QKV_ITER(1, 2 * t + 1, BB, BA)
    }
#undef QKV_ITER

    const float coefL = sc[0] * 0.125f * 1.44269504f;

    #pragma unroll
    for (int m = 0; m < 4; m++) {
        const int grow0 = bm * 128 + wm * 64 + m * 16 + (g << 2);
        #pragma unroll
        for (int n = 0; n < 4; n++) {
            const int gcol = bn * 128 + wn * 64 + n * 16 + l15;
            const float bv2 = bias[gcol];
            f32x4 c = acc[m][n];
            const int b = grow0 >> 12, s0 = grow0 & 4095;
            const int h = gcol >> 6, dk = gcol & 63;
            if (z == 0) {
                const size_t base = ((size_t)(b * 8 + h) * 4096 + s0) * 64 + dk;
                #pragma unroll
                for (int r = 0; r < 4; r++)
                    Qh[base + (size_t)r * 64] = bfbits((c[r] + bv2) * coefL);
            } else if (z == 1) {
                const float tdh = td[h];
                const size_t base = ((size_t)(b * 8 + h) * 4096 + s0) * 64 + dk;
                #pragma unroll
                for (int r = 0; r < 4; r++)
                    Kh[base + (size_t)r * 64] = bfbits((c[r] + bv2) * __expf(-tdh * (float)(s0 + r)));
            } else {
                ushort4v pk = { bfbits(c[0] + bv2), bfbits(c[1] + bv2),
                                bfbits(c[2] + bv2), bfbits(c[3] + bv2) };
                *(ushort4v*)&Vt[((size_t)(b * 8 + h) * 64 + dk) * 4096 + s0] = pk;
            }
        }
    }
}

// ---------------------------------------------------------------------------
// Output projection GEMM (R8-v3 structure; Wo read directly as fp32):
// A = ctx bf16 via gload16 dbuf LDS; B = Wo fp32 global-frag prefetch,
// converted at use. 128x64 tile, BK=64, 8 iters, 512 blocks XCD-swizzled.
// ---------------------------------------------------------------------------
__global__ __launch_bounds__(256) void gemm_out(
    const unsigned short* __restrict__ Actx, const float* __restrict__ Wo,
    const float* __restrict__ bias, float* __restrict__ Out)
{
    __shared__ __align__(16) char ALDS[2][16384];   // A tile 128 rows x 128B bf16

    const int id  = blockIdx.x;
    const int nid = (id & 7) * 64 + (id >> 3);
    const int bm  = nid >> 3;
    const int bn  = nid & 7;

    const int tid  = threadIdx.x;
    const int lane = tid & 63;
    const int w    = tid >> 6;
    const int wm   = w >> 1, wn = w & 1;
    const int l15  = lane & 15;
    const int g    = lane >> 4;

    const int lr  = lane >> 3;
    const int lc  = ((lane & 7) * 16) ^ (lr << 4);
    const char* asrc[4];
    #pragma unroll
    for (int j = 0; j < 4; j++)
        asrc[j] = (const char*)Actx + (size_t)(bm * 128 + w * 32 + j * 8 + lr) * 1024 + lc;
    int adst[4];
    #pragma unroll
    for (int j = 0; j < 4; j++) adst[j] = w * 4096 + j * 1024;

    const float* Bp[2];
    #pragma unroll
    for (int n = 0; n < 2; n++)
        Bp[n] = Wo + (size_t)(bn * 64 + wn * 32 + n * 16 + l15) * 512 + g * 8;

    f32x4 acc[4][2];
    #pragma unroll
    for (int m = 0; m < 4; m++)
        #pragma unroll
        for (int n = 0; n < 2; n++)
            acc[m][n] = (f32x4){0.f, 0.f, 0.f, 0.f};

    const int arow = l15;
    const int asw  = (arow & 7) << 4;

    #pragma unroll
    for (int j = 0; j < 4; j++) gload16(asrc[j], ALDS[0] + adst[j]);
    // B buffers: [n][k-half][2x f32x4]
    f32x4 BA[2][2][2], BB[2][2][2];
    #pragma unroll
    for (int n = 0; n < 2; n++) {
        BA[n][0][0] = *(const f32x4*)Bp[n];
        BA[n][0][1] = *(const f32x4*)(Bp[n] + 4);
        BA[n][1][0] = *(const f32x4*)(Bp[n] + 32);
        BA[n][1][1] = *(const f32x4*)(Bp[n] + 36);
    }

#define OUT_ITER(CUR, KK, BC, BN)                                                  \
    {                                                                              \
        asm volatile("s_waitcnt vmcnt(0)" ::: "memory");                           \
        __syncthreads();                                                           \
        if ((KK) < 7) {                                                            \
            _Pragma("unroll")                                                      \
            for (int j = 0; j < 4; j++)                                            \
                gload16(asrc[j] + (size_t)((KK) + 1) * 128,                        \
                        ALDS[(CUR) ^ 1] + adst[j]);                                \
            _Pragma("unroll")                                                      \
            for (int n = 0; n < 2; n++) {                                          \
                BN[n][0][0] = *(const f32x4*)(Bp[n] + (size_t)((KK) + 1) * 64);      \
                BN[n][0][1] = *(const f32x4*)(Bp[n] + (size_t)((KK) + 1) * 64 + 4);  \
                BN[n][1][0] = *(const f32x4*)(Bp[n] + (size_t)((KK) + 1) * 64 + 32); \
                BN[n][1][1] = *(const f32x4*)(Bp[n] + (size_t)((KK) + 1) * 64 + 36); \
            }                                                                      \
        }                                                                          \
        bf16x8 bfr[2][2];                                                          \
        _Pragma("unroll")                                                          \
        for (int n = 0; n < 2; n++) {                                              \
            bfr[n][0] = cvt8(BC[n][0][0], BC[n][0][1]);                            \
            bfr[n][1] = cvt8(BC[n][1][0], BC[n][1][1]);                            \
        }                                                                          \
        bf16x8 af[4][2];                                                           \
        _Pragma("unroll")                                                          \
        for (int m = 0; m < 4; m++) {                                              \
            const char* base = ALDS[CUR] + (wm * 64 + m * 16 + arow) * 128;        \
            af[m][0] = *(const bf16x8*)(base + ((g * 16) ^ asw));                  \
            af[m][1] = *(const bf16x8*)(base + ((64 + g * 16) ^ asw));             \
        }                                                                          \
        __builtin_amdgcn_s_setprio(1);                                             \
        _Pragma("unroll")                                                          \
        for (int m = 0; m < 4; m++)                                                \
            _Pragma("unroll")                                                      \
            for (int n = 0; n < 2; n++) {                                          \
                acc[m][n] = mfma16(af[m][0], bfr[n][0], acc[m][n]);                \
                acc[m][n] = mfma16(af[m][1], bfr[n][1], acc[m][n]);                \
            }                                                                      \
        __builtin_amdgcn_s_setprio(0);                                             \
    }

    #pragma unroll 1
    for (int t = 0; t < 4; ++t) {
        OUT_ITER(0, 2 * t, BA, BB)
        OUT_ITER(1, 2 * t + 1, BB, BA)
    }
#undef OUT_ITER

    #pragma unroll
    for (int m = 0; m < 4; m++) {
        const int grow0 = bm * 128 + wm * 64 + m * 16 + (g << 2);
        #pragma unroll
        for (int n = 0; n < 2; n++) {
            const int gcol = bn * 64 + wn * 32 + n * 16 + l15;
            const float bv2 = bias[gcol];
            f32x4 c = acc[m][n];
            #pragma unroll
            for (int r = 0; r < 4; r++)
                Out[(size_t)(grow0 + r) * 512 + gcol] = c[r] + bv2;
        }
    }
}

// ---------------------------------------------------------------------------
// Tail precompute v2 (unchanged from R8).
// ---------------------------------------------------------------------------
__global__ __launch_bounds__(512) void tail_pre(
    const unsigned short* __restrict__ Kh, const unsigned short* __restrict__ Vt,
    const float* __restrict__ td, const float* __restrict__ sc,
    unsigned short* __restrict__ Mt, float* __restrict__ SumV, float* __restrict__ KsL)
{
    __shared__ __align__(16) char KLDS[2][8192];
    __shared__ float redM[4][32][32];
    __shared__ float redv[64];
    __shared__ float redk[64];

    const int blk  = blockIdx.x;
    const int bh   = blk >> 1;
    const int half = blk & 1;
    const int h    = bh & 7;
    const int tid  = threadIdx.x;
    const int w    = tid >> 6;
    const int lane = tid & 63;
    const int l31  = lane & 31, hl = lane >> 5;
    const int d2q  = w & 1, d1q = (w >> 1) & 1, ksub = w >> 2;

    const int KT  = tail_tiles(td[h], sc[0]);
    const int K0  = KT * 64;
    const int nk  = 4096 - K0;
    const int kh0 = ((nk >> 1) + 63) & ~63;
    const int kcnt = half ? (nk - kh0) : kh0;
    const int kbeg = K0 + half * kh0;
    const int nch  = kcnt >> 6;

    const int lr = lane >> 3;
    const int r8 = (w * 8 + lr) & 7;
    const char* ksrc = (const char*)Kh + (size_t)(bh * 4096 + kbeg + w * 8 + lr) * 128
                     + (((lane & 7) * 16) ^ (r8 << 4));
    const int kdst = w * 1024;

    const unsigned short* Vp = Vt + (size_t)(bh * 64 + d2q * 32 + l31) * 4096 + kbeg;

    f32x16 macc = zero16();
    float sumv = 0.f, ksum = 0.f;

    if (nch > 0) gload16(ksrc, KLDS[0] + kdst);

    #pragma unroll 1
    for (int ch = 0; ch < nch; ++ch) {
        asm volatile("s_waitcnt vmcnt(0)" ::: "memory");
        __syncthreads();
        if (ch + 1 < nch)
            gload16(ksrc + (size_t)(ch + 1) * 8192, KLDS[(ch + 1) & 1] + kdst);
        const char* kb = KLDS[ch & 1];

        #pragma unroll
        for (int mf = 0; mf < 2; mf++) {
            const int kloc0 = ksub * 32 + mf * 16 + hl * 8;
            ushort8 kbv;
            #pragma unroll
            for (int e = 0; e < 8; e++) {
                const int row = kloc0 + e;
                kbv[e] = *(const unsigned short*)(kb + row * 128
                          + ((d1q * 64 + l31 * 2) ^ ((row & 7) << 4)));
            }
            if (d2q == 0) {
                #pragma unroll
                for (int e = 0; e < 8; e++) ksum += bf2f_u(kbv[e]);
            }
            bf16x8 av = *(const bf16x8*)(Vp + ch * 64 + kloc0);
            if (d1q == 0) {
                ushort8 au = __builtin_bit_cast(ushort8, av);
                #pragma unroll
                for (int e = 0; e < 8; e++) sumv += bf2f_u(au[e]);
            }
            macc = mfma32(av, __builtin_bit_cast(bf16x8, kbv), macc);
        }
    }

    sumv += __shfl_xor(sumv, 32);
    ksum += __shfl_xor(ksum, 32);

    const int quad = d2q * 2 + d1q;
    __syncthreads();
    if (ksub == 0) {
        #pragma unroll
        for (int r = 0; r < 16; r++) {
            const int row = (r & 3) + 8 * (r >> 2) + 4 * hl;
            redM[quad][row][l31] = macc[r];
        }
        if (d1q == 0 && hl == 0) redv[d2q * 32 + l31] = sumv;
        if (d2q == 0 && hl == 0) redk[d1q * 32 + l31] = ksum;
    }
    __syncthreads();
    if (ksub == 1) {
        unsigned short* Mb = Mt + (size_t)half * 16 * 4096 + (size_t)bh * 4096;
        #pragma unroll
        for (int r = 0; r < 16; r++) {
            const int row = (r & 3) + 8 * (r >> 2) + 4 * hl;
            const float mv = (macc[r] + redM[quad][row][l31]) * 0.6931472f;
            Mb[(size_t)(d2q * 32 + row) * 64 + d1q * 32 + l31] = bfbits(mv);
        }
        if (d1q == 0 && hl == 0)
            SumV[half * 1024 + bh * 64 + d2q * 32 + l31] = sumv + redv[d2q * 32 + l31];
        if (d2q == 0 && hl == 0)
            KsL[half * 1024 + bh * 64 + d1q * 32 + l31] = (ksum + redk[d1q * 32 + l31]) * 0.6931472f;
    }
}

// ---------------------------------------------------------------------------
// Flash attention over [0, KT*64) + linearized tail (unchanged from R8).
// ---------------------------------------------------------------------------
__global__ __launch_bounds__(256, 4) void attn_decay(
    const unsigned short* __restrict__ Qh, const unsigned short* __restrict__ Kh,
    const unsigned short* __restrict__ Vt, const float* __restrict__ td,
    const float* __restrict__ sc,
    const unsigned short* __restrict__ Mt, const float* __restrict__ SumV,
    const float* __restrict__ KsL, unsigned short* __restrict__ ctx)
{
    __shared__ __align__(16) char LDSB[32768];

    const int tid  = threadIdx.x;
    const int lane = tid & 63;
    const int w    = tid >> 6;
    const int qg   = w >> 1;
    const int ws   = w & 1;
    const int l31  = lane & 31;
    const int hl   = lane >> 5;

    const int i  = blockIdx.x;
    const int bh = ((i & 7) << 1) | ((i >> 9) & 1);
    const int qt = (i >> 3) & 63;
    const int h  = bh & 7;
    const int b  = bh >> 3;

    const int KT = tail_tiles(td[h], sc[0]);
    const int nk = 4096 - KT * 64;

    bf16x8 qf[4];
    {
        const unsigned short* Qp =
            Qh + ((size_t)bh * 4096 + qt * 64 + qg * 32 + l31) * 64 + hl * 8;
        #pragma unroll
        for (int c = 0; c < 4; c++)
            qf[c] = *(const bf16x8*)(Qp + c * 16);
    }

    f32x16 o0 = zero16(), o1 = zero16();
    float lp = 0.f;

    const char* kgp0; const char* kgp1; const char* vgp0; const char* vgp1;
    int ldsoff0, ldsoff1;
    {
        const size_t kbaseB = (size_t)bh * 4096 * 64 * 2;
        const size_t vbaseB = (size_t)bh * 64 * 4096 * 2;
        const int p0 = w * 2048 + lane * 16;
        const int r0 = p0 >> 7, c0 = p0 & 127, sw0 = (r0 & 7) << 4;
        const int p1 = w * 2048 + 1024 + lane * 16;
        const int r1 = p1 >> 7, c1 = p1 & 127, sw1 = (r1 & 7) << 4;
        kgp0 = (const char*)Kh + kbaseB + (size_t)r0 * 128  + (c0 ^ sw0);
        kgp1 = (const char*)Kh + kbaseB + (size_t)r1 * 128  + (c1 ^ sw1);
        vgp0 = (const char*)Vt + vbaseB + (size_t)r0 * 8192 + (c0 ^ sw0);
        vgp1 = (const char*)Vt + vbaseB + (size_t)r1 * 8192 + (c1 ^ sw1);
        ldsoff0 = w * 2048;
        ldsoff1 = w * 2048 + 1024;
    }
    gload16(kgp0, LDSB + ldsoff0);
    gload16(kgp1, LDSB + ldsoff1);
    gload16(vgp0, LDSB + 16384 + ldsoff0);
    gload16(vgp1, LDSB + 16384 + ldsoff1);
    kgp0 += 8192; kgp1 += 8192; vgp0 += 128; vgp1 += 128;

    const int krow = ws * 32 + l31;
    const int ksw  = (krow & 7) << 4;

#define ATTN_TILE(CUR, KT_IDX)                                                    \
    {                                                                             \
        asm volatile("s_waitcnt vmcnt(0)" ::: "memory");                          \
        __syncthreads();                                                          \
        if ((KT_IDX) + 1 < KT) {                                                  \
            gload16(kgp0, LDSB + ((CUR) ^ 1) * 8192 + ldsoff0);                   \
            gload16(kgp1, LDSB + ((CUR) ^ 1) * 8192 + ldsoff1);                   \
            gload16(vgp0, LDSB + 16384 + ((CUR) ^ 1) * 8192 + ldsoff0);           \
            gload16(vgp1, LDSB + 16384 + ((CUR) ^ 1) * 8192 + ldsoff1);           \
            kgp0 += 8192; kgp1 += 8192; vgp0 += 128; vgp1 += 128;                 \
        }                                                                         \
        const char* kb = LDSB + (CUR) * 8192;                                     \
        const char* vb = LDSB + 16384 + (CUR) * 8192;                             \
        f32x16 s = zero16();                                                      \
        __builtin_amdgcn_s_setprio(1);                                            \
        _Pragma("unroll")                                                         \
        for (int c = 0; c < 4; c++) {                                             \
            bf16x8 kf = *(const bf16x8*)(kb + krow * 128 + ((c * 32 + hl * 16) ^ ksw)); \
            s = mfma32(kf, qf[c], s);                                             \
        }                                                                         \
        __builtin_amdgcn_s_setprio(0);                                            \
        float p[16];                                                              \
        _Pragma("unroll")                                                         \
        for (int r = 0; r < 16; r++) {                                            \
            p[r] = __builtin_amdgcn_exp2f(s[r]);                                  \
            lp += p[r];                                                           \
        }                                                                         \
        unsigned int W0 = cvtpk(p[0], p[1]),   W1 = cvtpk(p[2], p[3]);            \
        unsigned int W2 = cvtpk(p[4], p[5]),   W3 = cvtpk(p[6], p[7]);            \
        unsigned int W4 = cvtpk(p[8], p[9]),   W5 = cvtpk(p[10], p[11]);          \
        unsigned int W6 = cvtpk(p[12], p[13]), W7 = cvtpk(p[14], p[15]);          \
        uint2v r02 = __builtin_amdgcn_permlane32_swap(W0, W2, false, false);      \
        uint2v r13 = __builtin_amdgcn_permlane32_swap(W1, W3, false, false);      \
        uint2v r46 = __builtin_amdgcn_permlane32_swap(W4, W6, false, false);      \
        uint2v r57 = __builtin_amdgcn_permlane32_swap(W5, W7, false, false);      \
        bf16x8 pa0 = __builtin_bit_cast(bf16x8, (uint4v){r02.x, r13.x, r02.y, r13.y}); \
        bf16x8 pa1 = __builtin_bit_cast(bf16x8, (uint4v){r46.x, r57.x, r46.y, r57.y}); \
        __builtin_amdgcn_s_setprio(1);                                            \
        {                                                                         \
            const int vr0  = l31;                                                 \
            const int vsw0 = (vr0 & 7) << 4;                                      \
            bf16x8 va = *(const bf16x8*)(vb + vr0 * 128 + ((ws * 64 + hl * 16) ^ vsw0));      \
            bf16x8 vb2 = *(const bf16x8*)(vb + vr0 * 128 + ((ws * 64 + 32 + hl * 16) ^ vsw0));\
            o0 = mfma32(pa0, va, o0);                                             \
            o0 = mfma32(pa1, vb2, o0);                                            \
            const int vr1  = 32 + l31;                                            \
            const int vsw1 = (vr1 & 7) << 4;                                      \
            bf16x8 vc = *(const bf16x8*)(vb + vr1 * 128 + ((ws * 64 + hl * 16) ^ vsw1));      \
            bf16x8 vd = *(const bf16x8*)(vb + vr1 * 128 + ((ws * 64 + 32 + hl * 16) ^ vsw1)); \
            o1 = mfma32(pa0, vc, o1);                                             \
            o1 = mfma32(pa1, vd, o1);                                             \
        }                                                                         \
        __builtin_amdgcn_s_setprio(0);                                            \
    }

    const int KT2 = KT >> 1;
    #pragma unroll 1
    for (int t = 0; t < KT2; ++t) {
        ATTN_TILE(0, 2 * t)
        ATTN_TILE(1, 2 * t + 1)
    }
    if (KT & 1) {
        ATTN_TILE(0, KT - 1)
    }
#undef ATTN_TILE

    if (ws == 0 && nk > 0) {
        float qk = 0.f;
        #pragma unroll
        for (int c = 0; c < 4; c++) {
            ushort8 qb = __builtin_bit_cast(ushort8, qf[c]);
            #pragma unroll
            for (int e = 0; e < 8; e++) {
                const int idx = c * 16 + hl * 8 + e;
                qk += bf2f_u(qb[e]) * (KsL[bh * 64 + idx] + KsL[1024 + bh * 64 + idx]);
            }
        }
        qk += __shfl_xor(qk, 32);
        if (hl == 0) lp += (float)nk + qk;

        #pragma unroll
        for (int half = 0; half < 2; half++) {
            const unsigned short* Mb = Mt + (size_t)half * 16 * 4096 + (size_t)bh * 4096;
            #pragma unroll
            for (int c = 0; c < 4; c++) {
                bf16x8 m0 = *(const bf16x8*)(Mb + (size_t)l31 * 64 + c * 16 + hl * 8);
                bf16x8 m1 = *(const bf16x8*)(Mb + (size_t)(32 + l31) * 64 + c * 16 + hl * 8);
                o0 = mfma32(qf[c], m0, o0);
                o1 = mfma32(qf[c], m1, o1);
            }
        }
        const float sv0 = SumV[bh * 64 + l31]      + SumV[1024 + bh * 64 + l31];
        const float sv1 = SumV[bh * 64 + 32 + l31] + SumV[1024 + bh * 64 + 32 + l31];
        #pragma unroll
        for (int r = 0; r < 16; r++) { o0[r] += sv0; o1[r] += sv1; }
    }

    float lw = lp + __shfl_xor(lp, 32);
    __syncthreads();
    float* lscr = (float*)(LDSB + 16384);
    if (lane < 32)
        lscr[(qg * 2 + ws) * 32 + lane] = lw;
    __syncthreads();
    const float pl2 = lscr[(qg * 2 + (ws ^ 1)) * 32 + l31];
    const float myscale = 1.f / (lw + pl2);
    #pragma unroll
    for (int rc = 0; rc < 4; rc++)
        #pragma unroll
        for (int j = 0; j < 4; j++) {
            const float a = lanepull(myscale, rc * 8 + hl * 4 + j);
            o0[rc * 4 + j] *= a;
            o1[rc * 4 + j] *= a;
        }
    __syncthreads();
    float* Oscr = (float*)(LDSB + qg * 8192);
    if (ws == 1) {
        #pragma unroll
        for (int reg = 0; reg < 16; reg++) {
            const int row = (reg & 3) + 8 * (reg >> 2) + 4 * hl;
            Oscr[row * 64 + l31]      = o0[reg];
            Oscr[row * 64 + 32 + l31] = o1[reg];
        }
    }
    __syncthreads();
    if (ws == 0) {
        #pragma unroll
        for (int reg = 0; reg < 16; reg++) {
            const int row = (reg & 3) + 8 * (reg >> 2) + 4 * hl;
            const float v0 = o0[reg] + Oscr[row * 64 + l31];
            const float v1 = o1[reg] + Oscr[row * 64 + 32 + l31];
            const int srow_ = qt * 64 + qg * 32 + row;
            const size_t idx = ((size_t)b * 4096 + srow_) * 512 + h * 64;
            ctx[idx + l31]      = bfbits(v0);
            ctx[idx + 32 + l31] = bfbits(v1);
        }
    }
}

// ---------------------------------------------------------------------------
extern "C" void kernel_launch(void* const* d_in, const int* in_sizes, int n_in,
                              void* d_out, int out_size, void* d_ws, size_t ws_size,
                              hipStream_t stream)
{
    (void)in_sizes; (void)n_in; (void)out_size; (void)ws_size;
    const float* q  = (const float*)d_in[0];
    const float* k  = (const float*)d_in[1];
    const float* v  = (const float*)d_in[2];
    const float* Wq = (const float*)d_in[3];
    const float* bq = (const float*)d_in[4];
    const float* Wk = (const float*)d_in[5];
    const float* bk = (const float*)d_in[6];
    const float* Wv = (const float*)d_in[7];
    const float* bv = (const float*)d_in[8];
    const float* Wo = (const float*)d_in[9];
    const float* bo = (const float*)d_in[10];
    const float* td = (const float*)d_in[11];
    const float* sc = (const float*)d_in[12];

    // d_ws: Qh, Kh, Vt, ctx (8 MB each) = 32 MB
    unsigned short* Qh  = (unsigned short*)d_ws;
    unsigned short* Kh  = Qh + (size_t)16 * 4096 * 64;
    unsigned short* Vt  = Kh + (size_t)16 * 4096 * 64;
    unsigned short* ctx = Vt + (size_t)16 * 4096 * 64;

    // tail scratch in d_out (fully overwritten by gemm_out afterwards)
    unsigned short* Mt   = (unsigned short*)d_out;                     // 2*16*4096 bf16
    float*          SumV = (float*)((char*)d_out + 2 * 16 * 4096 * 2); // 2*1024 f32
    float*          KsL  = SumV + 2 * 1024;                            // 2*1024 f32

    gemm_qkv<<<dim3(768), 256, 0, stream>>>(q, k, v, Wq, Wk, Wv, bq, bk, bv, td, sc, Qh, Kh, Vt);
    tail_pre<<<dim3(32), 512, 0, stream>>>(Kh, Vt, td, sc, Mt, SumV, KsL);
    attn_decay<<<dim3(1024), 256, 0, stream>>>(Qh, Kh, Vt, td, sc, Mt, SumV, KsL, ctx);
    gemm_out<<<dim3(512), 256, 0, stream>>>(ctx, Wo, bo, (float*)d_out);
}

// Round 13
// 122.433 us; speedup vs baseline: 1.2311x; 1.2311x over previous
//
#include <hip/hip_runtime.h>
#include <hip/hip_bf16.h>
#include <stdint.h>

typedef __attribute__((ext_vector_type(8))) __bf16 bf16x8;
typedef __attribute__((ext_vector_type(4))) float f32x4;
typedef __attribute__((ext_vector_type(16))) float f32x16;
typedef __attribute__((ext_vector_type(8))) unsigned short ushort8;
typedef __attribute__((ext_vector_type(4))) unsigned short ushort4v;
typedef __attribute__((ext_vector_type(2))) unsigned int uint2v;
typedef __attribute__((ext_vector_type(4))) unsigned int uint4v;

__device__ __forceinline__ unsigned short bfbits(float x) {
    __bf16 b = (__bf16)x;
    return __builtin_bit_cast(unsigned short, b);
}
__device__ __forceinline__ float bf2f_u(unsigned short u) {
    return __builtin_bit_cast(float, (unsigned int)u << 16);
}

__device__ __forceinline__ f32x4 mfma16(bf16x8 a, bf16x8 b, f32x4 c) {
    return __builtin_amdgcn_mfma_f32_16x16x32_bf16(a, b, c, 0, 0, 0);
}
__device__ __forceinline__ f32x16 mfma32(bf16x8 a, bf16x8 b, f32x16 c) {
    return __builtin_amdgcn_mfma_f32_32x32x16_bf16(a, b, c, 0, 0, 0);
}

__device__ __forceinline__ unsigned int cvtpk(float lo, float hi) {
    unsigned int r;
    asm("v_cvt_pk_bf16_f32 %0, %1, %2" : "=v"(r) : "v"(lo), "v"(hi));
    return r;
}

__device__ __forceinline__ float lanepull(float src, int srcl) {
    return __builtin_bit_cast(float,
        __builtin_amdgcn_ds_bpermute(srcl * 4, __builtin_bit_cast(int, src)));
}

__device__ __forceinline__ void gload16(const void* g, void* l) {
    __builtin_amdgcn_global_load_lds(
        (const __attribute__((address_space(1))) unsigned int*)g,
        (__attribute__((address_space(3))) unsigned int*)l, 16, 0, 0);
}

__device__ __forceinline__ f32x16 zero16() {
    f32x16 r;
    #pragma unroll
    for (int i = 0; i < 16; i++) r[i] = 0.f;
    return r;
}

__device__ __forceinline__ int tail_tiles(float tdh, float scale) {
    float cut = 5.3f + __logf(fmaxf(scale, 1e-20f));
    cut = fmaxf(cut, 0.f);
    tdh = fmaxf(tdh, 1e-8f);
    int kt = (int)ceilf(cut / (tdh * 64.f));
    if (kt < 1) kt = 1;
    if (kt > 64) kt = 64;
    return kt;
}

// ---------------------------------------------------------------------------
// Weight conversion: Wq,Wk,Wv,Wo fp32 -> bf16 slabs (262144 elems each).
// ---------------------------------------------------------------------------
__global__ __launch_bounds__(256) void wconv(
    const float* __restrict__ Wq, const float* __restrict__ Wk,
    const float* __restrict__ Wv, const float* __restrict__ Wo,
    unsigned short* __restrict__ Wbf)
{
    const int t    = blockIdx.x * 256 + threadIdx.x;   // 131072 threads
    const int slab = t >> 15;
    const int off8 = t & 32767;
    const float* src = (slab == 0) ? Wq : (slab == 1) ? Wk : (slab == 2) ? Wv : Wo;
    float4 a = ((const float4*)(src + off8 * 8))[0];
    float4 b = ((const float4*)(src + off8 * 8))[1];
    uint4v pk = { cvtpk(a.x, a.y), cvtpk(a.z, a.w), cvtpk(b.x, b.y), cvtpk(b.z, b.w) };
    *(uint4v*)(Wbf + (size_t)slab * 262144 + off8 * 8) = pk;
}

// ---------------------------------------------------------------------------
// Merged Q/K/V projection GEMM v3 (R8) + burst decorrelation:
// (1) per-block K-rotation (start = (id*7)&15, cyclic iteration) so
//     co-resident blocks fetch different addresses each round trip;
// (2) s_sleep stagger at entry to de-phase the burst clock.
// A fp32 staged via global_load_lds into XOR-swizzled dbuf LDS, converted
// bf16 at frag read; B bf16 frags from global (L2) 1-iter prefetch.
// 768 blocks XCD-swizzled, 128x128 tile, BK=32, 16 iters.
// ---------------------------------------------------------------------------
__global__ __launch_bounds__(256) void gemm_qkv(
    const float* __restrict__ q, const float* __restrict__ k, const float* __restrict__ v,
    const unsigned short* __restrict__ Wbf,
    const float* __restrict__ bq, const float* __restrict__ bk, const float* __restrict__ bv,
    const float* __restrict__ td, const float* __restrict__ sc,
    unsigned short* __restrict__ Qh, unsigned short* __restrict__ Kh,
    unsigned short* __restrict__ Vt)
{
    __shared__ __align__(16) char ALDS[2][16384];   // A tile 128 rows x 128B fp32

    const int id  = blockIdx.x;
    const int nid = (id & 7) * 96 + (id >> 3);
    const int z   = nid >> 8;
    const int rem = nid & 255;
    const int bm  = rem >> 2;
    const int bn  = rem & 3;

    // burst de-phasing: sleep 0..3 x 256 cycles depending on block id
    {
        const int ph = (id >> 3) & 3;
        for (int s = 0; s < ph; ++s) __builtin_amdgcn_s_sleep(4);
    }
    const int start = (id * 7) & 15;   // K-rotation offset

    const float* A0   = (z == 0) ? q  : (z == 1) ? k  : v;
    const float* bias = (z == 0) ? bq : (z == 1) ? bk : bv;

    const int tid  = threadIdx.x;
    const int lane = tid & 63;
    const int w    = tid >> 6;
    const int wm   = w >> 1, wn = w & 1;
    const int l15  = lane & 15;
    const int g    = lane >> 4;

    // staging source (pre-swizzled): lane covers row r = w*32 + j*8 + lane>>3
    const int lr  = lane >> 3;
    const int lc  = ((lane & 7) * 16) ^ (lr << 4);
    const char* asrc[4];
    #pragma unroll
    for (int j = 0; j < 4; j++)
        asrc[j] = (const char*)A0 + (size_t)(bm * 128 + w * 32 + j * 8 + lr) * 2048 + lc;
    int adst[4];
    #pragma unroll
    for (int j = 0; j < 4; j++) adst[j] = w * 4096 + j * 1024;

    // B fragment bases (bf16 weights, global)
    const unsigned short* Bp[4];
    #pragma unroll
    for (int n = 0; n < 4; n++)
        Bp[n] = Wbf + (size_t)z * 262144
              + (size_t)(bn * 128 + wn * 64 + n * 16 + l15) * 512 + g * 8;

    f32x4 acc[4][4];
    #pragma unroll
    for (int m = 0; m < 4; m++)
        #pragma unroll
        for (int n = 0; n < 4; n++)
            acc[m][n] = (f32x4){0.f, 0.f, 0.f, 0.f};

    // A-frag read offsets (swizzled)
    const int arow = l15;
    const int asw  = (arow & 7) << 4;

    // prologue: stage kk=start -> buf0, load B frags for start
    #pragma unroll
    for (int j = 0; j < 4; j++) gload16(asrc[j] + (size_t)start * 128, ALDS[0] + adst[j]);
    bf16x8 BA[4], BB[4];
    #pragma unroll
    for (int n = 0; n < 4; n++) BA[n] = *(const bf16x8*)(Bp[n] + (size_t)start * 32);

#define QKV_ITER(CUR, I, BC, BN)                                                   \
    {                                                                              \
        asm volatile("s_waitcnt vmcnt(0)" ::: "memory");                           \
        __syncthreads();                                                           \
        if ((I) < 15) {                                                            \
            const int kkn = (start + (I) + 1) & 15;                                \
            _Pragma("unroll")                                                      \
            for (int j = 0; j < 4; j++)                                            \
                gload16(asrc[j] + (size_t)kkn * 128,                               \
                        ALDS[(CUR) ^ 1] + adst[j]);                                \
            _Pragma("unroll")                                                      \
            for (int n = 0; n < 4; n++)                                            \
                BN[n] = *(const bf16x8*)(Bp[n] + (size_t)kkn * 32);                \
        }                                                                          \
        bf16x8 af[4];                                                              \
        _Pragma("unroll")                                                          \
        for (int m = 0; m < 4; m++) {                                              \
            const char* base = ALDS[CUR] + (wm * 64 + m * 16 + arow) * 128;        \
            f32x4 v0 = *(const f32x4*)(base + ((g * 32) ^ asw));                   \
            f32x4 v1 = *(const f32x4*)(base + (((g * 32) | 16) ^ asw));            \
            uint4v pk = { cvtpk(v0.x, v0.y), cvtpk(v0.z, v0.w),                    \
                          cvtpk(v1.x, v1.y), cvtpk(v1.z, v1.w) };                  \
            af[m] = __builtin_bit_cast(bf16x8, pk);                                \
        }                                                                          \
        __builtin_amdgcn_s_setprio(1);                                             \
        _Pragma("unroll")                                                          \
        for (int m = 0; m < 4; m++)                                                \
            _Pragma("unroll")                                                      \
            for (int n = 0; n < 4; n++)                                            \
                acc[m][n] = mfma16(af[m], BC[n], acc[m][n]);                       \
        __builtin_amdgcn_s_setprio(0);                                             \
    }

    #pragma unroll 1
    for (int t = 0; t < 8; ++t) {
        QKV_ITER(0, 2 * t, BA, BB)
        QKV_ITER(1, 2 * t + 1, BB, BA)
    }
#undef QKV_ITER

    const float coefL = sc[0] * 0.125f * 1.44269504f;

    #pragma unroll
    for (int m = 0; m < 4; m++) {
        const int grow0 = bm * 128 + wm * 64 + m * 16 + (g << 2);
        #pragma unroll
        for (int n = 0; n < 4; n++) {
            const int gcol = bn * 128 + wn * 64 + n * 16 + l15;
            const float bv2 = bias[gcol];
            f32x4 c = acc[m][n];
            const int b = grow0 >> 12, s0 = grow0 & 4095;
            const int h = gcol >> 6, dk = gcol & 63;
            if (z == 0) {
                const size_t base = ((size_t)(b * 8 + h) * 4096 + s0) * 64 + dk;
                #pragma unroll
                for (int r = 0; r < 4; r++)
                    Qh[base + (size_t)r * 64] = bfbits((c[r] + bv2) * coefL);
            } else if (z == 1) {
                const float tdh = td[h];
                const size_t base = ((size_t)(b * 8 + h) * 4096 + s0) * 64 + dk;
                #pragma unroll
                for (int r = 0; r < 4; r++)
                    Kh[base + (size_t)r * 64] = bfbits((c[r] + bv2) * __expf(-tdh * (float)(s0 + r)));
            } else {
                ushort4v pk = { bfbits(c[0] + bv2), bfbits(c[1] + bv2),
                                bfbits(c[2] + bv2), bfbits(c[3] + bv2) };
                *(ushort4v*)&Vt[((size_t)(b * 8 + h) * 64 + dk) * 4096 + s0] = pk;
            }
        }
    }
}

// ---------------------------------------------------------------------------
// Output projection GEMM v3 (R8, unchanged): A = ctx bf16 via gload16 dbuf
// LDS; B = Wo bf16 global-frag prefetch. 128x64 tile, BK=64, 8 iters,
// 512 blocks XCD-swizzled.
// ---------------------------------------------------------------------------
__global__ __launch_bounds__(256) void gemm_out(
    const unsigned short* __restrict__ Actx, const unsigned short* __restrict__ Wob,
    const float* __restrict__ bias, float* __restrict__ Out)
{
    __shared__ __align__(16) char ALDS[2][16384];   // A tile 128 rows x 128B bf16

    const int id  = blockIdx.x;
    const int nid = (id & 7) * 64 + (id >> 3);
    const int bm  = nid >> 3;
    const int bn  = nid & 7;

    const int tid  = threadIdx.x;
    const int lane = tid & 63;
    const int w    = tid >> 6;
    const int wm   = w >> 1, wn = w & 1;
    const int l15  = lane & 15;
    const int g    = lane >> 4;

    const int lr  = lane >> 3;
    const int lc  = ((lane & 7) * 16) ^ (lr << 4);
    const char* asrc[4];
    #pragma unroll
    for (int j = 0; j < 4; j++)
        asrc[j] = (const char*)Actx + (size_t)(bm * 128 + w * 32 + j * 8 + lr) * 1024 + lc;
    int adst[4];
    #pragma unroll
    for (int j = 0; j < 4; j++) adst[j] = w * 4096 + j * 1024;

    const unsigned short* Bp[2];
    #pragma unroll
    for (int n = 0; n < 2; n++)
        Bp[n] = Wob + (size_t)(bn * 64 + wn * 32 + n * 16 + l15) * 512 + g * 8;

    f32x4 acc[4][2];
    #pragma unroll
    for (int m = 0; m < 4; m++)
        #pragma unroll
        for (int n = 0; n < 2; n++)
            acc[m][n] = (f32x4){0.f, 0.f, 0.f, 0.f};

    const int arow = l15;
    const int asw  = (arow & 7) << 4;

    #pragma unroll
    for (int j = 0; j < 4; j++) gload16(asrc[j], ALDS[0] + adst[j]);
    bf16x8 BA[2][2], BB[2][2];
    #pragma unroll
    for (int n = 0; n < 2; n++) {
        BA[n][0] = *(const bf16x8*)Bp[n];
        BA[n][1] = *(const bf16x8*)(Bp[n] + 32);
    }

#define OUT_ITER(CUR, KK, BC, BN)                                                  \
    {                                                                              \
        asm volatile("s_waitcnt vmcnt(0)" ::: "memory");                           \
        __syncthreads();                                                           \
        if ((KK) < 7) {                                                            \
            _Pragma("unroll")                                                      \
            for (int j = 0; j < 4; j++)                                            \
                gload16(asrc[j] + (size_t)((KK) + 1) * 128,                        \
                        ALDS[(CUR) ^ 1] + adst[j]);                                \
            _Pragma("unroll")                                                      \
            for (int n = 0; n < 2; n++) {                                          \
                BN[n][0] = *(const bf16x8*)(Bp[n] + (size_t)((KK) + 1) * 64);      \
                BN[n][1] = *(const bf16x8*)(Bp[n] + (size_t)((KK) + 1) * 64 + 32); \
            }                                                                      \
        }                                                                          \
        bf16x8 af[4][2];                                                           \
        _Pragma("unroll")                                                          \
        for (int m = 0; m < 4; m++) {                                              \
            const char* base = ALDS[CUR] + (wm * 64 + m * 16 + arow) * 128;        \
            af[m][0] = *(const bf16x8*)(base + ((g * 16) ^ asw));                  \
            af[m][1] = *(const bf16x8*)(base + ((64 + g * 16) ^ asw));             \
        }                                                                          \
        __builtin_amdgcn_s_setprio(1);                                             \
        _Pragma("unroll")                                                          \
        for (int m = 0; m < 4; m++)                                                \
            _Pragma("unroll")                                                      \
            for (int n = 0; n < 2; n++) {                                          \
                acc[m][n] = mfma16(af[m][0], BC[n][0], acc[m][n]);                 \
                acc[m][n] = mfma16(af[m][1], BC[n][1], acc[m][n]);                 \
            }                                                                      \
        __builtin_amdgcn_s_setprio(0);                                             \
    }

    #pragma unroll 1
    for (int t = 0; t < 4; ++t) {
        OUT_ITER(0, 2 * t, BA, BB)
        OUT_ITER(1, 2 * t + 1, BB, BA)
    }
#undef OUT_ITER

    #pragma unroll
    for (int m = 0; m < 4; m++) {
        const int grow0 = bm * 128 + wm * 64 + m * 16 + (g << 2);
        #pragma unroll
        for (int n = 0; n < 2; n++) {
            const int gcol = bn * 64 + wn * 32 + n * 16 + l15;
            const float bv2 = bias[gcol];
            f32x4 c = acc[m][n];
            #pragma unroll
            for (int r = 0; r < 4; r++)
                Out[(size_t)(grow0 + r) * 512 + gcol] = c[r] + bv2;
        }
    }
}

// ---------------------------------------------------------------------------
// Tail precompute v2 (unchanged from R8).
// ---------------------------------------------------------------------------
__global__ __launch_bounds__(512) void tail_pre(
    const unsigned short* __restrict__ Kh, const unsigned short* __restrict__ Vt,
    const float* __restrict__ td, const float* __restrict__ sc,
    unsigned short* __restrict__ Mt, float* __restrict__ SumV, float* __restrict__ KsL)
{
    __shared__ __align__(16) char KLDS[2][8192];
    __shared__ float redM[4][32][32];
    __shared__ float redv[64];
    __shared__ float redk[64];

    const int blk  = blockIdx.x;
    const int bh   = blk >> 1;
    const int half = blk & 1;
    const int h    = bh & 7;
    const int tid  = threadIdx.x;
    const int w    = tid >> 6;
    const int lane = tid & 63;
    const int l31  = lane & 31, hl = lane >> 5;
    const int d2q  = w & 1, d1q = (w >> 1) & 1, ksub = w >> 2;

    const int KT  = tail_tiles(td[h], sc[0]);
    const int K0  = KT * 64;
    const int nk  = 4096 - K0;
    const int kh0 = ((nk >> 1) + 63) & ~63;
    const int kcnt = half ? (nk - kh0) : kh0;
    const int kbeg = K0 + half * kh0;
    const int nch  = kcnt >> 6;

    const int lr = lane >> 3;
    const int r8 = (w * 8 + lr) & 7;
    const char* ksrc = (const char*)Kh + (size_t)(bh * 4096 + kbeg + w * 8 + lr) * 128
                     + (((lane & 7) * 16) ^ (r8 << 4));
    const int kdst = w * 1024;

    const unsigned short* Vp = Vt + (size_t)(bh * 64 + d2q * 32 + l31) * 4096 + kbeg;

    f32x16 macc = zero16();
    float sumv = 0.f, ksum = 0.f;

    if (nch > 0) gload16(ksrc, KLDS[0] + kdst);

    #pragma unroll 1
    for (int ch = 0; ch < nch; ++ch) {
        asm volatile("s_waitcnt vmcnt(0)" ::: "memory");
        __syncthreads();
        if (ch + 1 < nch)
            gload16(ksrc + (size_t)(ch + 1) * 8192, KLDS[(ch + 1) & 1] + kdst);
        const char* kb = KLDS[ch & 1];

        #pragma unroll
        for (int mf = 0; mf < 2; mf++) {
            const int kloc0 = ksub * 32 + mf * 16 + hl * 8;
            ushort8 kbv;
            #pragma unroll
            for (int e = 0; e < 8; e++) {
                const int row = kloc0 + e;
                kbv[e] = *(const unsigned short*)(kb + row * 128
                          + ((d1q * 64 + l31 * 2) ^ ((row & 7) << 4)));
            }
            if (d2q == 0) {
                #pragma unroll
                for (int e = 0; e < 8; e++) ksum += bf2f_u(kbv[e]);
            }
            bf16x8 av = *(const bf16x8*)(Vp + ch * 64 + kloc0);
            if (d1q == 0) {
                ushort8 au = __builtin_bit_cast(ushort8, av);
                #pragma unroll
                for (int e = 0; e < 8; e++) sumv += bf2f_u(au[e]);
            }
            macc = mfma32(av, __builtin_bit_cast(bf16x8, kbv), macc);
        }
    }

    sumv += __shfl_xor(sumv, 32);
    ksum += __shfl_xor(ksum, 32);

    const int quad = d2q * 2 + d1q;
    __syncthreads();
    if (ksub == 0) {
        #pragma unroll
        for (int r = 0; r < 16; r++) {
            const int row = (r & 3) + 8 * (r >> 2) + 4 * hl;
            redM[quad][row][l31] = macc[r];
        }
        if (d1q == 0 && hl == 0) redv[d2q * 32 + l31] = sumv;
        if (d2q == 0 && hl == 0) redk[d1q * 32 + l31] = ksum;
    }
    __syncthreads();
    if (ksub == 1) {
        unsigned short* Mb = Mt + (size_t)half * 16 * 4096 + (size_t)bh * 4096;
        #pragma unroll
        for (int r = 0; r < 16; r++) {
            const int row = (r & 3) + 8 * (r >> 2) + 4 * hl;
            const float mv = (macc[r] + redM[quad][row][l31]) * 0.6931472f;
            Mb[(size_t)(d2q * 32 + row) * 64 + d1q * 32 + l31] = bfbits(mv);
        }
        if (d1q == 0 && hl == 0)
            SumV[half * 1024 + bh * 64 + d2q * 32 + l31] = sumv + redv[d2q * 32 + l31];
        if (d2q == 0 && hl == 0)
            KsL[half * 1024 + bh * 64 + d1q * 32 + l31] = (ksum + redk[d1q * 32 + l31]) * 0.6931472f;
    }
}

// ---------------------------------------------------------------------------
// Flash attention over [0, KT*64) + linearized tail (unchanged from R8).
// ---------------------------------------------------------------------------
__global__ __launch_bounds__(256, 4) void attn_decay(
    const unsigned short* __restrict__ Qh, const unsigned short* __restrict__ Kh,
    const unsigned short* __restrict__ Vt, const float* __restrict__ td,
    const float* __restrict__ sc,
    const unsigned short* __restrict__ Mt, const float* __restrict__ SumV,
    const float* __restrict__ KsL, unsigned short* __restrict__ ctx)
{
    __shared__ __align__(16) char LDSB[32768];

    const int tid  = threadIdx.x;
    const int lane = tid & 63;
    const int w    = tid >> 6;
    const int qg   = w >> 1;
    const int ws   = w & 1;
    const int l31  = lane & 31;
    const int hl   = lane >> 5;

    const int i  = blockIdx.x;
    const int bh = ((i & 7) << 1) | ((i >> 9) & 1);
    const int qt = (i >> 3) & 63;
    const int h  = bh & 7;
    const int b  = bh >> 3;

    const int KT = tail_tiles(td[h], sc[0]);
    const int nk = 4096 - KT * 64;

    bf16x8 qf[4];
    {
        const unsigned short* Qp =
            Qh + ((size_t)bh * 4096 + qt * 64 + qg * 32 + l31) * 64 + hl * 8;
        #pragma unroll
        for (int c = 0; c < 4; c++)
            qf[c] = *(const bf16x8*)(Qp + c * 16);
    }

    f32x16 o0 = zero16(), o1 = zero16();
    float lp = 0.f;

    const char* kgp0; const char* kgp1; const char* vgp0; const char* vgp1;
    int ldsoff0, ldsoff1;
    {
        const size_t kbaseB = (size_t)bh * 4096 * 64 * 2;
        const size_t vbaseB = (size_t)bh * 64 * 4096 * 2;
        const int p0 = w * 2048 + lane * 16;
        const int r0 = p0 >> 7, c0 = p0 & 127, sw0 = (r0 & 7) << 4;
        const int p1 = w * 2048 + 1024 + lane * 16;
        const int r1 = p1 >> 7, c1 = p1 & 127, sw1 = (r1 & 7) << 4;
        kgp0 = (const char*)Kh + kbaseB + (size_t)r0 * 128  + (c0 ^ sw0);
        kgp1 = (const char*)Kh + kbaseB + (size_t)r1 * 128  + (c1 ^ sw1);
        vgp0 = (const char*)Vt + vbaseB + (size_t)r0 * 8192 + (c0 ^ sw0);
        vgp1 = (const char*)Vt + vbaseB + (size_t)r1 * 8192 + (c1 ^ sw1);
        ldsoff0 = w * 2048;
        ldsoff1 = w * 2048 + 1024;
    }
    gload16(kgp0, LDSB + ldsoff0);
    gload16(kgp1, LDSB + ldsoff1);
    gload16(vgp0, LDSB + 16384 + ldsoff0);
    gload16(vgp1, LDSB + 16384 + ldsoff1);
    kgp0 += 8192; kgp1 += 8192; vgp0 += 128; vgp1 += 128;

    const int krow = ws * 32 + l31;
    const int ksw  = (krow & 7) << 4;

#define ATTN_TILE(CUR, KT_IDX)                                                    \
    {                                                                             \
        asm volatile("s_waitcnt vmcnt(0)" ::: "memory");                          \
        __syncthreads();                                                          \
        if ((KT_IDX) + 1 < KT) {                                                  \
            gload16(kgp0, LDSB + ((CUR) ^ 1) * 8192 + ldsoff0);                   \
            gload16(kgp1, LDSB + ((CUR) ^ 1) * 8192 + ldsoff1);                   \
            gload16(vgp0, LDSB + 16384 + ((CUR) ^ 1) * 8192 + ldsoff0);           \
            gload16(vgp1, LDSB + 16384 + ((CUR) ^ 1) * 8192 + ldsoff1);           \
            kgp0 += 8192; kgp1 += 8192; vgp0 += 128; vgp1 += 128;                 \
        }                                                                         \
        const char* kb = LDSB + (CUR) * 8192;                                     \
        const char* vb = LDSB + 16384 + (CUR) * 8192;                             \
        f32x16 s = zero16();                                                      \
        __builtin_amdgcn_s_setprio(1);                                            \
        _Pragma("unroll")                                                         \
        for (int c = 0; c < 4; c++) {                                             \
            bf16x8 kf = *(const bf16x8*)(kb + krow * 128 + ((c * 32 + hl * 16) ^ ksw)); \
            s = mfma32(kf, qf[c], s);                                             \
        }                                                                         \
        __builtin_amdgcn_s_setprio(0);                                            \
        float p[16];                                                              \
        _Pragma("unroll")                                                         \
        for (int r = 0; r < 16; r++) {                                            \
            p[r] = __builtin_amdgcn_exp2f(s[r]);                                  \
            lp += p[r];                                                           \
        }                                                                         \
        unsigned int W0 = cvtpk(p[0], p[1]),   W1 = cvtpk(p[2], p[3]);            \
        unsigned int W2 = cvtpk(p[4], p[5]),   W3 = cvtpk(p[6], p[7]);            \
        unsigned int W4 = cvtpk(p[8], p[9]),   W5 = cvtpk(p[10], p[11]);          \
        unsigned int W6 = cvtpk(p[12], p[13]), W7 = cvtpk(p[14], p[15]);          \
        uint2v r02 = __builtin_amdgcn_permlane32_swap(W0, W2, false, false);      \
        uint2v r13 = __builtin_amdgcn_permlane32_swap(W1, W3, false, false);      \
        uint2v r46 = __builtin_amdgcn_permlane32_swap(W4, W6, false, false);      \
        uint2v r57 = __builtin_amdgcn_permlane32_swap(W5, W7, false, false);      \
        bf16x8 pa0 = __builtin_bit_cast(bf16x8, (uint4v){r02.x, r13.x, r02.y, r13.y}); \
        bf16x8 pa1 = __builtin_bit_cast(bf16x8, (uint4v){r46.x, r57.x, r46.y, r57.y}); \
        __builtin_amdgcn_s_setprio(1);                                            \
        {                                                                         \
            const int vr0  = l31;                                                 \
            const int vsw0 = (vr0 & 7) << 4;                                      \
            bf16x8 va = *(const bf16x8*)(vb + vr0 * 128 + ((ws * 64 + hl * 16) ^ vsw0));      \
            bf16x8 vb2 = *(const bf16x8*)(vb + vr0 * 128 + ((ws * 64 + 32 + hl * 16) ^ vsw0));\
            o0 = mfma32(pa0, va, o0);                                             \
            o0 = mfma32(pa1, vb2, o0);                                            \
            const int vr1  = 32 + l31;                                            \
            const int vsw1 = (vr1 & 7) << 4;                                      \
            bf16x8 vc = *(const bf16x8*)(vb + vr1 * 128 + ((ws * 64 + hl * 16) ^ vsw1));      \
            bf16x8 vd = *(const bf16x8*)(vb + vr1 * 128 + ((ws * 64 + 32 + hl * 16) ^ vsw1)); \
            o1 = mfma32(pa0, vc, o1);                                             \
            o1 = mfma32(pa1, vd, o1);                                             \
        }                                                                         \
        __builtin_amdgcn_s_setprio(0);                                            \
    }

    const int KT2 = KT >> 1;
    #pragma unroll 1
    for (int t = 0; t < KT2; ++t) {
        ATTN_TILE(0, 2 * t)
        ATTN_TILE(1, 2 * t + 1)
    }
    if (KT & 1) {
        ATTN_TILE(0, KT - 1)
    }
#undef ATTN_TILE

    if (ws == 0 && nk > 0) {
        float qk = 0.f;
        #pragma unroll
        for (int c = 0; c < 4; c++) {
            ushort8 qb = __builtin_bit_cast(ushort8, qf[c]);
            #pragma unroll
            for (int e = 0; e < 8; e++) {
                const int idx = c * 16 + hl * 8 + e;
                qk += bf2f_u(qb[e]) * (KsL[bh * 64 + idx] + KsL[1024 + bh * 64 + idx]);
            }
        }
        qk += __shfl_xor(qk, 32);
        if (hl == 0) lp += (float)nk + qk;

        #pragma unroll
        for (int half = 0; half < 2; half++) {
            const unsigned short* Mb = Mt + (size_t)half * 16 * 4096 + (size_t)bh * 4096;
            #pragma unroll
            for (int c = 0; c < 4; c++) {
                bf16x8 m0 = *(const bf16x8*)(Mb + (size_t)l31 * 64 + c * 16 + hl * 8);
                bf16x8 m1 = *(const bf16x8*)(Mb + (size_t)(32 + l31) * 64 + c * 16 + hl * 8);
                o0 = mfma32(qf[c], m0, o0);
                o1 = mfma32(qf[c], m1, o1);
            }
        }
        const float sv0 = SumV[bh * 64 + l31]      + SumV[1024 + bh * 64 + l31];
        const float sv1 = SumV[bh * 64 + 32 + l31] + SumV[1024 + bh * 64 + 32 + l31];
        #pragma unroll
        for (int r = 0; r < 16; r++) { o0[r] += sv0; o1[r] += sv1; }
    }

    float lw = lp + __shfl_xor(lp, 32);
    __syncthreads();
    float* lscr = (float*)(LDSB + 16384);
    if (lane < 32)
        lscr[(qg * 2 + ws) * 32 + lane] = lw;
    __syncthreads();
    const float pl2 = lscr[(qg * 2 + (ws ^ 1)) * 32 + l31];
    const float myscale = 1.f / (lw + pl2);
    #pragma unroll
    for (int rc = 0; rc < 4; rc++)
        #pragma unroll
        for (int j = 0; j < 4; j++) {
            const float a = lanepull(myscale, rc * 8 + hl * 4 + j);
            o0[rc * 4 + j] *= a;
            o1[rc * 4 + j] *= a;
        }
    __syncthreads();
    float* Oscr = (float*)(LDSB + qg * 8192);
    if (ws == 1) {
        #pragma unroll
        for (int reg = 0; reg < 16; reg++) {
            const int row = (reg & 3) + 8 * (reg >> 2) + 4 * hl;
            Oscr[row * 64 + l31]      = o0[reg];
            Oscr[row * 64 + 32 + l31] = o1[reg];
        }
    }
    __syncthreads();
    if (ws == 0) {
        #pragma unroll
        for (int reg = 0; reg < 16; reg++) {
            const int row = (reg & 3) + 8 * (reg >> 2) + 4 * hl;
            const float v0 = o0[reg] + Oscr[row * 64 + l31];
            const float v1 = o1[reg] + Oscr[row * 64 + 32 + l31];
            const int srow_ = qt * 64 + qg * 32 + row;
            const size_t idx = ((size_t)b * 4096 + srow_) * 512 + h * 64;
            ctx[idx + l31]      = bfbits(v0);
            ctx[idx + 32 + l31] = bfbits(v1);
        }
    }
}

// ---------------------------------------------------------------------------
extern "C" void kernel_launch(void* const* d_in, const int* in_sizes, int n_in,
                              void* d_out, int out_size, void* d_ws, size_t ws_size,
                              hipStream_t stream)
{
    (void)in_sizes; (void)n_in; (void)out_size; (void)ws_size;
    const float* q  = (const float*)d_in[0];
    const float* k  = (const float*)d_in[1];
    const float* v  = (const float*)d_in[2];
    const float* Wq = (const float*)d_in[3];
    const float* bq = (const float*)d_in[4];
    const float* Wk = (const float*)d_in[5];
    const float* bk = (const float*)d_in[6];
    const float* Wv = (const float*)d_in[7];
    const float* bv = (const float*)d_in[8];
    const float* Wo = (const float*)d_in[9];
    const float* bo = (const float*)d_in[10];
    const float* td = (const float*)d_in[11];
    const float* sc = (const float*)d_in[12];

    // d_ws: Qh, Kh, Vt, ctx (8 MB each) + Wbf (2 MB) = 34 MB
    unsigned short* Qh  = (unsigned short*)d_ws;
    unsigned short* Kh  = Qh + (size_t)16 * 4096 * 64;
    unsigned short* Vt  = Kh + (size_t)16 * 4096 * 64;
    unsigned short* ctx = Vt + (size_t)16 * 4096 * 64;
    unsigned short* Wbf = ctx + (size_t)16 * 4096 * 64;

    // tail scratch in d_out (fully overwritten by gemm_out afterwards)
    unsigned short* Mt   = (unsigned short*)d_out;                     // 2*16*4096 bf16
    float*          SumV = (float*)((char*)d_out + 2 * 16 * 4096 * 2); // 2*1024 f32
    float*          KsL  = SumV + 2 * 1024;                            // 2*1024 f32

    wconv<<<dim3(512), 256, 0, stream>>>(Wq, Wk, Wv, Wo, Wbf);
    gemm_qkv<<<dim3(768), 256, 0, stream>>>(q, k, v, Wbf, bq, bk, bv, td, sc, Qh, Kh, Vt);
    tail_pre<<<dim3(32), 512, 0, stream>>>(Kh, Vt, td, sc, Mt, SumV, KsL);
    attn_decay<<<dim3(1024), 256, 0, stream>>>(Qh, Kh, Vt, td, sc, Mt, SumV, KsL, ctx);
    gemm_out<<<dim3(512), 256, 0, stream>>>(ctx, Wbf + (size_t)3 * 262144, bo, (float*)d_out);
}

// Round 14
// 115.916 us; speedup vs baseline: 1.3003x; 1.0562x over previous
//
#include <hip/hip_runtime.h>
#include <hip/hip_bf16.h>
#include <stdint.h>

typedef __attribute__((ext_vector_type(8))) __bf16 bf16x8;
typedef __attribute__((ext_vector_type(4))) float f32x4;
typedef __attribute__((ext_vector_type(16))) float f32x16;
typedef __attribute__((ext_vector_type(8))) unsigned short ushort8;
typedef __attribute__((ext_vector_type(4))) unsigned short ushort4v;
typedef __attribute__((ext_vector_type(2))) unsigned int uint2v;
typedef __attribute__((ext_vector_type(4))) unsigned int uint4v;

__device__ __forceinline__ unsigned short bfbits(float x) {
    __bf16 b = (__bf16)x;
    return __builtin_bit_cast(unsigned short, b);
}
__device__ __forceinline__ float bf2f_u(unsigned short u) {
    return __builtin_bit_cast(float, (unsigned int)u << 16);
}

__device__ __forceinline__ f32x4 mfma16(bf16x8 a, bf16x8 b, f32x4 c) {
    return __builtin_amdgcn_mfma_f32_16x16x32_bf16(a, b, c, 0, 0, 0);
}
__device__ __forceinline__ f32x16 mfma32(bf16x8 a, bf16x8 b, f32x16 c) {
    return __builtin_amdgcn_mfma_f32_32x32x16_bf16(a, b, c, 0, 0, 0);
}

__device__ __forceinline__ unsigned int cvtpk(float lo, float hi) {
    unsigned int r;
    asm("v_cvt_pk_bf16_f32 %0, %1, %2" : "=v"(r) : "v"(lo), "v"(hi));
    return r;
}

__device__ __forceinline__ float lanepull(float src, int srcl) {
    return __builtin_bit_cast(float,
        __builtin_amdgcn_ds_bpermute(srcl * 4, __builtin_bit_cast(int, src)));
}

__device__ __forceinline__ void gload16(const void* g, void* l) {
    __builtin_amdgcn_global_load_lds(
        (const __attribute__((address_space(1))) unsigned int*)g,
        (__attribute__((address_space(3))) unsigned int*)l, 16, 0, 0);
}

__device__ __forceinline__ f32x16 zero16() {
    f32x16 r;
    #pragma unroll
    for (int i = 0; i < 16; i++) r[i] = 0.f;
    return r;
}

__device__ __forceinline__ int tail_tiles(float tdh, float scale) {
    float cut = 5.3f + __logf(fmaxf(scale, 1e-20f));
    cut = fmaxf(cut, 0.f);
    tdh = fmaxf(tdh, 1e-8f);
    int kt = (int)ceilf(cut / (tdh * 64.f));
    if (kt < 1) kt = 1;
    if (kt > 64) kt = 64;
    return kt;
}

// ---------------------------------------------------------------------------
// Weight conversion: Wq,Wk,Wv,Wo fp32 -> bf16 slabs (262144 elems each).
// ---------------------------------------------------------------------------
__global__ __launch_bounds__(256) void wconv(
    const float* __restrict__ Wq, const float* __restrict__ Wk,
    const float* __restrict__ Wv, const float* __restrict__ Wo,
    unsigned short* __restrict__ Wbf)
{
    const int t    = blockIdx.x * 256 + threadIdx.x;
    const int slab = t >> 15;
    const int off8 = t & 32767;
    const float* src = (slab == 0) ? Wq : (slab == 1) ? Wk : (slab == 2) ? Wv : Wo;
    float4 a = ((const float4*)(src + off8 * 8))[0];
    float4 b = ((const float4*)(src + off8 * 8))[1];
    uint4v pk = { cvtpk(a.x, a.y), cvtpk(a.z, a.w), cvtpk(b.x, b.y), cvtpk(b.z, b.w) };
    *(uint4v*)(Wbf + (size_t)slab * 262144 + off8 * 8) = pk;
}

// ---------------------------------------------------------------------------
// Merged Q/K/V projection GEMM v3 (exact R8). A fp32 staged via
// global_load_lds into XOR-swizzled dbuf LDS, converted bf16 at frag read;
// B bf16 frags from global (L2) with 1-iter register prefetch.
// 768 blocks XCD-swizzled, 128x128 tile, BK=32, 16 iters.
// ---------------------------------------------------------------------------
__global__ __launch_bounds__(256) void gemm_qkv(
    const float* __restrict__ q, const float* __restrict__ k, const float* __restrict__ v,
    const unsigned short* __restrict__ Wbf,
    const float* __restrict__ bq, const float* __restrict__ bk, const float* __restrict__ bv,
    const float* __restrict__ td, const float* __restrict__ sc,
    unsigned short* __restrict__ Qh, unsigned short* __restrict__ Kh,
    unsigned short* __restrict__ Vt)
{
    __shared__ __align__(16) char ALDS[2][16384];

    const int id  = blockIdx.x;
    const int nid = (id & 7) * 96 + (id >> 3);
    const int z   = nid >> 8;
    const int rem = nid & 255;
    const int bm  = rem >> 2;
    const int bn  = rem & 3;

    const float* A0   = (z == 0) ? q  : (z == 1) ? k  : v;
    const float* bias = (z == 0) ? bq : (z == 1) ? bk : bv;

    const int tid  = threadIdx.x;
    const int lane = tid & 63;
    const int w    = tid >> 6;
    const int wm   = w >> 1, wn = w & 1;
    const int l15  = lane & 15;
    const int g    = lane >> 4;

    const int lr  = lane >> 3;
    const int lc  = ((lane & 7) * 16) ^ (lr << 4);
    const char* asrc[4];
    #pragma unroll
    for (int j = 0; j < 4; j++)
        asrc[j] = (const char*)A0 + (size_t)(bm * 128 + w * 32 + j * 8 + lr) * 2048 + lc;
    int adst[4];
    #pragma unroll
    for (int j = 0; j < 4; j++) adst[j] = w * 4096 + j * 1024;

    const unsigned short* Bp[4];
    #pragma unroll
    for (int n = 0; n < 4; n++)
        Bp[n] = Wbf + (size_t)z * 262144
              + (size_t)(bn * 128 + wn * 64 + n * 16 + l15) * 512 + g * 8;

    f32x4 acc[4][4];
    #pragma unroll
    for (int m = 0; m < 4; m++)
        #pragma unroll
        for (int n = 0; n < 4; n++)
            acc[m][n] = (f32x4){0.f, 0.f, 0.f, 0.f};

    const int arow = l15;
    const int asw  = (arow & 7) << 4;

    #pragma unroll
    for (int j = 0; j < 4; j++) gload16(asrc[j], ALDS[0] + adst[j]);
    bf16x8 BA[4], BB[4];
    #pragma unroll
    for (int n = 0; n < 4; n++) BA[n] = *(const bf16x8*)Bp[n];

#define QKV_ITER(CUR, KK, BC, BN)                                                  \
    {                                                                              \
        asm volatile("s_waitcnt vmcnt(0)" ::: "memory");                           \
        __syncthreads();                                                           \
        if ((KK) < 15) {                                                           \
            _Pragma("unroll")                                                      \
            for (int j = 0; j < 4; j++)                                            \
                gload16(asrc[j] + (size_t)((KK) + 1) * 128,                        \
                        ALDS[(CUR) ^ 1] + adst[j]);                                \
            _Pragma("unroll")                                                      \
            for (int n = 0; n < 4; n++)                                            \
                BN[n] = *(const bf16x8*)(Bp[n] + (size_t)((KK) + 1) * 32);         \
        }                                                                          \
        bf16x8 af[4];                                                              \
        _Pragma("unroll")                                                          \
        for (int m = 0; m < 4; m++) {                                              \
            const char* base = ALDS[CUR] + (wm * 64 + m * 16 + arow) * 128;        \
            f32x4 v0 = *(const f32x4*)(base + ((g * 32) ^ asw));                   \
            f32x4 v1 = *(const f32x4*)(base + (((g * 32) | 16) ^ asw));            \
            uint4v pk = { cvtpk(v0.x, v0.y), cvtpk(v0.z, v0.w),                    \
                          cvtpk(v1.x, v1.y), cvtpk(v1.z, v1.w) };                  \
            af[m] = __builtin_bit_cast(bf16x8, pk);                                \
        }                                                                          \
        __builtin_amdgcn_s_setprio(1);                                             \
        _Pragma("unroll")                                                          \
        for (int m = 0; m < 4; m++)                                                \
            _Pragma("unroll")                                                      \
            for (int n = 0; n < 4; n++)                                            \
                acc[m][n] = mfma16(af[m], BC[n], acc[m][n]);                       \
        __builtin_amdgcn_s_setprio(0);                                             \
    }

    #pragma unroll 1
    for (int t = 0; t < 8; ++t) {
        QKV_ITER(0, 2 * t, BA, BB)
        QKV_ITER(1, 2 * t + 1, BB, BA)
    }
#undef QKV_ITER

    const float coefL = sc[0] * 0.125f * 1.44269504f;

    #pragma unroll
    for (int m = 0; m < 4; m++) {
        const int grow0 = bm * 128 + wm * 64 + m * 16 + (g << 2);
        #pragma unroll
        for (int n = 0; n < 4; n++) {
            const int gcol = bn * 128 + wn * 64 + n * 16 + l15;
            const float bv2 = bias[gcol];
            f32x4 c = acc[m][n];
            const int b = grow0 >> 12, s0 = grow0 & 4095;
            const int h = gcol >> 6, dk = gcol & 63;
            if (z == 0) {
                const size_t base = ((size_t)(b * 8 + h) * 4096 + s0) * 64 + dk;
                #pragma unroll
                for (int r = 0; r < 4; r++)
                    Qh[base + (size_t)r * 64] = bfbits((c[r] + bv2) * coefL);
            } else if (z == 1) {
                const float tdh = td[h];
                const size_t base = ((size_t)(b * 8 + h) * 4096 + s0) * 64 + dk;
                #pragma unroll
                for (int r = 0; r < 4; r++)
                    Kh[base + (size_t)r * 64] = bfbits((c[r] + bv2) * __expf(-tdh * (float)(s0 + r)));
            } else {
                ushort4v pk = { bfbits(c[0] + bv2), bfbits(c[1] + bv2),
                                bfbits(c[2] + bv2), bfbits(c[3] + bv2) };
                *(ushort4v*)&Vt[((size_t)(b * 8 + h) * 64 + dk) * 4096 + s0] = pk;
            }
        }
    }
}

// ---------------------------------------------------------------------------
// Output projection GEMM v3 (exact R8).
// ---------------------------------------------------------------------------
__global__ __launch_bounds__(256) void gemm_out(
    const unsigned short* __restrict__ Actx, const unsigned short* __restrict__ Wob,
    const float* __restrict__ bias, float* __restrict__ Out)
{
    __shared__ __align__(16) char ALDS[2][16384];

    const int id  = blockIdx.x;
    const int nid = (id & 7) * 64 + (id >> 3);
    const int bm  = nid >> 3;
    const int bn  = nid & 7;

    const int tid  = threadIdx.x;
    const int lane = tid & 63;
    const int w    = tid >> 6;
    const int wm   = w >> 1, wn = w & 1;
    const int l15  = lane & 15;
    const int g    = lane >> 4;

    const int lr  = lane >> 3;
    const int lc  = ((lane & 7) * 16) ^ (lr << 4);
    const char* asrc[4];
    #pragma unroll
    for (int j = 0; j < 4; j++)
        asrc[j] = (const char*)Actx + (size_t)(bm * 128 + w * 32 + j * 8 + lr) * 1024 + lc;
    int adst[4];
    #pragma unroll
    for (int j = 0; j < 4; j++) adst[j] = w * 4096 + j * 1024;

    const unsigned short* Bp[2];
    #pragma unroll
    for (int n = 0; n < 2; n++)
        Bp[n] = Wob + (size_t)(bn * 64 + wn * 32 + n * 16 + l15) * 512 + g * 8;

    f32x4 acc[4][2];
    #pragma unroll
    for (int m = 0; m < 4; m++)
        #pragma unroll
        for (int n = 0; n < 2; n++)
            acc[m][n] = (f32x4){0.f, 0.f, 0.f, 0.f};

    const int arow = l15;
    const int asw  = (arow & 7) << 4;

    #pragma unroll
    for (int j = 0; j < 4; j++) gload16(asrc[j], ALDS[0] + adst[j]);
    bf16x8 BA[2][2], BB[2][2];
    #pragma unroll
    for (int n = 0; n < 2; n++) {
        BA[n][0] = *(const bf16x8*)Bp[n];
        BA[n][1] = *(const bf16x8*)(Bp[n] + 32);
    }

#define OUT_ITER(CUR, KK, BC, BN)                                                  \
    {                                                                              \
        asm volatile("s_waitcnt vmcnt(0)" ::: "memory");                           \
        __syncthreads();                                                           \
        if ((KK) < 7) {                                                            \
            _Pragma("unroll")                                                      \
            for (int j = 0; j < 4; j++)                                            \
                gload16(asrc[j] + (size_t)((KK) + 1) * 128,                        \
                        ALDS[(CUR) ^ 1] + adst[j]);                                \
            _Pragma("unroll")                                                      \
            for (int n = 0; n < 2; n++) {                                          \
                BN[n][0] = *(const bf16x8*)(Bp[n] + (size_t)((KK) + 1) * 64);      \
                BN[n][1] = *(const bf16x8*)(Bp[n] + (size_t)((KK) + 1) * 64 + 32); \
            }                                                                      \
        }                                                                          \
        bf16x8 af[4][2];                                                           \
        _Pragma("unroll")                                                          \
        for (int m = 0; m < 4; m++) {                                              \
            const char* base = ALDS[CUR] + (wm * 64 + m * 16 + arow) * 128;        \
            af[m][0] = *(const bf16x8*)(base + ((g * 16) ^ asw));                  \
            af[m][1] = *(const bf16x8*)(base + ((64 + g * 16) ^ asw));             \
        }                                                                          \
        __builtin_amdgcn_s_setprio(1);                                             \
        _Pragma("unroll")                                                          \
        for (int m = 0; m < 4; m++)                                                \
            _Pragma("unroll")                                                      \
            for (int n = 0; n < 2; n++) {                                          \
                acc[m][n] = mfma16(af[m][0], BC[n][0], acc[m][n]);                 \
                acc[m][n] = mfma16(af[m][1], BC[n][1], acc[m][n]);                 \
            }                                                                      \
        __builtin_amdgcn_s_setprio(0);                                             \
    }

    #pragma unroll 1
    for (int t = 0; t < 4; ++t) {
        OUT_ITER(0, 2 * t, BA, BB)
        OUT_ITER(1, 2 * t + 1, BB, BA)
    }
#undef OUT_ITER

    #pragma unroll
    for (int m = 0; m < 4; m++) {
        const int grow0 = bm * 128 + wm * 64 + m * 16 + (g << 2);
        #pragma unroll
        for (int n = 0; n < 2; n++) {
            const int gcol = bn * 64 + wn * 32 + n * 16 + l15;
            const float bv2 = bias[gcol];
            f32x4 c = acc[m][n];
            #pragma unroll
            for (int r = 0; r < 4; r++)
                Out[(size_t)(grow0 + r) * 512 + gcol] = c[r] + bv2;
        }
    }
}

// ---------------------------------------------------------------------------
// Tail precompute v3: 128 blocks = 16 bh x 8 k-parts (4x the parallelism of
// v2; the 32-block version left 87% of the GPU idle and its ~27-chunk serial
// lockstep loop dominated). Each part computes a PARTIAL Mt/SumV/KsL slab;
// attn_decay sums the 8 slabs (cheap: bf16 mfma each).
// ---------------------------------------------------------------------------
__global__ __launch_bounds__(512) void tail_pre(
    const unsigned short* __restrict__ Kh, const unsigned short* __restrict__ Vt,
    const float* __restrict__ td, const float* __restrict__ sc,
    unsigned short* __restrict__ Mt, float* __restrict__ SumV, float* __restrict__ KsL)
{
    __shared__ __align__(16) char KLDS[2][8192];
    __shared__ float redM[4][32][32];
    __shared__ float redv[64];
    __shared__ float redk[64];

    const int blk  = blockIdx.x;
    const int bh   = blk >> 3;
    const int part = blk & 7;
    const int h    = bh & 7;
    const int tid  = threadIdx.x;
    const int w    = tid >> 6;
    const int lane = tid & 63;
    const int l31  = lane & 31, hl = lane >> 5;
    const int d2q  = w & 1, d1q = (w >> 1) & 1, ksub = w >> 2;

    const int KT   = tail_tiles(td[h], sc[0]);
    const int K0   = KT * 64;
    const int nk   = 4096 - K0;
    const int q64  = nk >> 6;                    // 64-key chunks in the tail
    const int qb   = q64 >> 3, qr = q64 & 7;
    const int nch  = qb + (part < qr ? 1 : 0);
    const int ch0  = part * qb + (part < qr ? part : qr);
    const int kbeg = K0 + ch0 * 64;

    const int lr = lane >> 3;
    const int r8 = (w * 8 + lr) & 7;
    const char* ksrc = (const char*)Kh + (size_t)(bh * 4096 + kbeg + w * 8 + lr) * 128
                     + (((lane & 7) * 16) ^ (r8 << 4));
    const int kdst = w * 1024;

    const unsigned short* Vp = Vt + (size_t)(bh * 64 + d2q * 32 + l31) * 4096 + kbeg;

    f32x16 macc = zero16();
    float sumv = 0.f, ksum = 0.f;

    if (nch > 0) gload16(ksrc, KLDS[0] + kdst);

    #pragma unroll 1
    for (int ch = 0; ch < nch; ++ch) {
        asm volatile("s_waitcnt vmcnt(0)" ::: "memory");
        __syncthreads();
        if (ch + 1 < nch)
            gload16(ksrc + (size_t)(ch + 1) * 8192, KLDS[(ch + 1) & 1] + kdst);
        const char* kb = KLDS[ch & 1];

        #pragma unroll
        for (int mf = 0; mf < 2; mf++) {
            const int kloc0 = ksub * 32 + mf * 16 + hl * 8;
            ushort8 kbv;
            #pragma unroll
            for (int e = 0; e < 8; e++) {
                const int row = kloc0 + e;
                kbv[e] = *(const unsigned short*)(kb + row * 128
                          + ((d1q * 64 + l31 * 2) ^ ((row & 7) << 4)));
            }
            if (d2q == 0) {
                #pragma unroll
                for (int e = 0; e < 8; e++) ksum += bf2f_u(kbv[e]);
            }
            bf16x8 av = *(const bf16x8*)(Vp + ch * 64 + kloc0);
            if (d1q == 0) {
                ushort8 au = __builtin_bit_cast(ushort8, av);
                #pragma unroll
                for (int e = 0; e < 8; e++) sumv += bf2f_u(au[e]);
            }
            macc = mfma32(av, __builtin_bit_cast(bf16x8, kbv), macc);
        }
    }

    sumv += __shfl_xor(sumv, 32);
    ksum += __shfl_xor(ksum, 32);

    const int quad = d2q * 2 + d1q;
    __syncthreads();
    if (ksub == 0) {
        #pragma unroll
        for (int r = 0; r < 16; r++) {
            const int row = (r & 3) + 8 * (r >> 2) + 4 * hl;
            redM[quad][row][l31] = macc[r];
        }
        if (d1q == 0 && hl == 0) redv[d2q * 32 + l31] = sumv;
        if (d2q == 0 && hl == 0) redk[d1q * 32 + l31] = ksum;
    }
    __syncthreads();
    if (ksub == 1) {
        unsigned short* Mb = Mt + (size_t)part * 16 * 4096 + (size_t)bh * 4096;
        #pragma unroll
        for (int r = 0; r < 16; r++) {
            const int row = (r & 3) + 8 * (r >> 2) + 4 * hl;
            const float mv = (macc[r] + redM[quad][row][l31]) * 0.6931472f;
            Mb[(size_t)(d2q * 32 + row) * 64 + d1q * 32 + l31] = bfbits(mv);
        }
        if (d1q == 0 && hl == 0)
            SumV[part * 1024 + bh * 64 + d2q * 32 + l31] = sumv + redv[d2q * 32 + l31];
        if (d2q == 0 && hl == 0)
            KsL[part * 1024 + bh * 64 + d1q * 32 + l31] = (ksum + redk[d1q * 32 + l31]) * 0.6931472f;
    }
}

// ---------------------------------------------------------------------------
// Flash attention over [0, KT*64) + linearized tail (8 partial slabs).
// ---------------------------------------------------------------------------
__global__ __launch_bounds__(256, 4) void attn_decay(
    const unsigned short* __restrict__ Qh, const unsigned short* __restrict__ Kh,
    const unsigned short* __restrict__ Vt, const float* __restrict__ td,
    const float* __restrict__ sc,
    const unsigned short* __restrict__ Mt, const float* __restrict__ SumV,
    const float* __restrict__ KsL, unsigned short* __restrict__ ctx)
{
    __shared__ __align__(16) char LDSB[32768];

    const int tid  = threadIdx.x;
    const int lane = tid & 63;
    const int w    = tid >> 6;
    const int qg   = w >> 1;
    const int ws   = w & 1;
    const int l31  = lane & 31;
    const int hl   = lane >> 5;

    const int i  = blockIdx.x;
    const int bh = ((i & 7) << 1) | ((i >> 9) & 1);
    const int qt = (i >> 3) & 63;
    const int h  = bh & 7;
    const int b  = bh >> 3;

    const int KT = tail_tiles(td[h], sc[0]);
    const int nk = 4096 - KT * 64;

    bf16x8 qf[4];
    {
        const unsigned short* Qp =
            Qh + ((size_t)bh * 4096 + qt * 64 + qg * 32 + l31) * 64 + hl * 8;
        #pragma unroll
        for (int c = 0; c < 4; c++)
            qf[c] = *(const bf16x8*)(Qp + c * 16);
    }

    f32x16 o0 = zero16(), o1 = zero16();
    float lp = 0.f;

    const char* kgp0; const char* kgp1; const char* vgp0; const char* vgp1;
    int ldsoff0, ldsoff1;
    {
        const size_t kbaseB = (size_t)bh * 4096 * 64 * 2;
        const size_t vbaseB = (size_t)bh * 64 * 4096 * 2;
        const int p0 = w * 2048 + lane * 16;
        const int r0 = p0 >> 7, c0 = p0 & 127, sw0 = (r0 & 7) << 4;
        const int p1 = w * 2048 + 1024 + lane * 16;
        const int r1 = p1 >> 7, c1 = p1 & 127, sw1 = (r1 & 7) << 4;
        kgp0 = (const char*)Kh + kbaseB + (size_t)r0 * 128  + (c0 ^ sw0);
        kgp1 = (const char*)Kh + kbaseB + (size_t)r1 * 128  + (c1 ^ sw1);
        vgp0 = (const char*)Vt + vbaseB + (size_t)r0 * 8192 + (c0 ^ sw0);
        vgp1 = (const char*)Vt + vbaseB + (size_t)r1 * 8192 + (c1 ^ sw1);
        ldsoff0 = w * 2048;
        ldsoff1 = w * 2048 + 1024;
    }
    gload16(kgp0, LDSB + ldsoff0);
    gload16(kgp1, LDSB + ldsoff1);
    gload16(vgp0, LDSB + 16384 + ldsoff0);
    gload16(vgp1, LDSB + 16384 + ldsoff1);
    kgp0 += 8192; kgp1 += 8192; vgp0 += 128; vgp1 += 128;

    const int krow = ws * 32 + l31;
    const int ksw  = (krow & 7) << 4;

#define ATTN_TILE(CUR, KT_IDX)                                                    \
    {                                                                             \
        asm volatile("s_waitcnt vmcnt(0)" ::: "memory");                          \
        __syncthreads();                                                          \
        if ((KT_IDX) + 1 < KT) {                                                  \
            gload16(kgp0, LDSB + ((CUR) ^ 1) * 8192 + ldsoff0);                   \
            gload16(kgp1, LDSB + ((CUR) ^ 1) * 8192 + ldsoff1);                   \
            gload16(vgp0, LDSB + 16384 + ((CUR) ^ 1) * 8192 + ldsoff0);           \
            gload16(vgp1, LDSB + 16384 + ((CUR) ^ 1) * 8192 + ldsoff1);           \
            kgp0 += 8192; kgp1 += 8192; vgp0 += 128; vgp1 += 128;                 \
        }                                                                         \
        const char* kb = LDSB + (CUR) * 8192;                                     \
        const char* vb = LDSB + 16384 + (CUR) * 8192;                             \
        f32x16 s = zero16();                                                      \
        __builtin_amdgcn_s_setprio(1);                                            \
        _Pragma("unroll")                                                         \
        for (int c = 0; c < 4; c++) {                                             \
            bf16x8 kf = *(const bf16x8*)(kb + krow * 128 + ((c * 32 + hl * 16) ^ ksw)); \
            s = mfma32(kf, qf[c], s);                                             \
        }                                                                         \
        __builtin_amdgcn_s_setprio(0);                                            \
        float p[16];                                                              \
        _Pragma("unroll")                                                         \
        for (int r = 0; r < 16; r++) {                                            \
            p[r] = __builtin_amdgcn_exp2f(s[r]);                                  \
            lp += p[r];                                                           \
        }                                                                         \
        unsigned int W0 = cvtpk(p[0], p[1]),   W1 = cvtpk(p[2], p[3]);            \
        unsigned int W2 = cvtpk(p[4], p[5]),   W3 = cvtpk(p[6], p[7]);            \
        unsigned int W4 = cvtpk(p[8], p[9]),   W5 = cvtpk(p[10], p[11]);          \
        unsigned int W6 = cvtpk(p[12], p[13]), W7 = cvtpk(p[14], p[15]);          \
        uint2v r02 = __builtin_amdgcn_permlane32_swap(W0, W2, false, false);      \
        uint2v r13 = __builtin_amdgcn_permlane32_swap(W1, W3, false, false);      \
        uint2v r46 = __builtin_amdgcn_permlane32_swap(W4, W6, false, false);      \
        uint2v r57 = __builtin_amdgcn_permlane32_swap(W5, W7, false, false);      \
        bf16x8 pa0 = __builtin_bit_cast(bf16x8, (uint4v){r02.x, r13.x, r02.y, r13.y}); \
        bf16x8 pa1 = __builtin_bit_cast(bf16x8, (uint4v){r46.x, r57.x, r46.y, r57.y}); \
        __builtin_amdgcn_s_setprio(1);                                            \
        {                                                                         \
            const int vr0  = l31;                                                 \
            const int vsw0 = (vr0 & 7) << 4;                                      \
            bf16x8 va = *(const bf16x8*)(vb + vr0 * 128 + ((ws * 64 + hl * 16) ^ vsw0));      \
            bf16x8 vb2 = *(const bf16x8*)(vb + vr0 * 128 + ((ws * 64 + 32 + hl * 16) ^ vsw0));\
            o0 = mfma32(pa0, va, o0);                                             \
            o0 = mfma32(pa1, vb2, o0);                                            \
            const int vr1  = 32 + l31;                                            \
            const int vsw1 = (vr1 & 7) << 4;                                      \
            bf16x8 vc = *(const bf16x8*)(vb + vr1 * 128 + ((ws * 64 + hl * 16) ^ vsw1));      \
            bf16x8 vd = *(const bf16x8*)(vb + vr1 * 128 + ((ws * 64 + 32 + hl * 16) ^ vsw1)); \
            o1 = mfma32(pa0, vc, o1);                                             \
            o1 = mfma32(pa1, vd, o1);                                             \
        }                                                                         \
        __builtin_amdgcn_s_setprio(0);                                            \
    }

    const int KT2 = KT >> 1;
    #pragma unroll 1
    for (int t = 0; t < KT2; ++t) {
        ATTN_TILE(0, 2 * t)
        ATTN_TILE(1, 2 * t + 1)
    }
    if (KT & 1) {
        ATTN_TILE(0, KT - 1)
    }
#undef ATTN_TILE

    // ---- linearized tail (8 partial slabs): o += SumV + q*Mt ; l += nk + q*KsL ----
    if (ws == 0 && nk > 0) {
        float qk = 0.f;
        #pragma unroll
        for (int c = 0; c < 4; c++) {
            ushort8 qb2 = __builtin_bit_cast(ushort8, qf[c]);
            #pragma unroll
            for (int e = 0; e < 8; e++) {
                const int idx = c * 16 + hl * 8 + e;
                float ks = 0.f;
                #pragma unroll
                for (int part = 0; part < 8; part++)
                    ks += KsL[part * 1024 + bh * 64 + idx];
                qk += bf2f_u(qb2[e]) * ks;
            }
        }
        qk += __shfl_xor(qk, 32);
        if (hl == 0) lp += (float)nk + qk;

        #pragma unroll 1
        for (int part = 0; part < 8; part++) {
            const unsigned short* Mb = Mt + (size_t)part * 16 * 4096 + (size_t)bh * 4096;
            #pragma unroll
            for (int c = 0; c < 4; c++) {
                bf16x8 m0 = *(const bf16x8*)(Mb + (size_t)l31 * 64 + c * 16 + hl * 8);
                bf16x8 m1 = *(const bf16x8*)(Mb + (size_t)(32 + l31) * 64 + c * 16 + hl * 8);
                o0 = mfma32(qf[c], m0, o0);
                o1 = mfma32(qf[c], m1, o1);
            }
        }
        float sv0 = 0.f, sv1 = 0.f;
        #pragma unroll
        for (int part = 0; part < 8; part++) {
            sv0 += SumV[part * 1024 + bh * 64 + l31];
            sv1 += SumV[part * 1024 + bh * 64 + 32 + l31];
        }
        #pragma unroll
        for (int r = 0; r < 16; r++) { o0[r] += sv0; o1[r] += sv1; }
    }

    float lw = lp + __shfl_xor(lp, 32);
    __syncthreads();
    float* lscr = (float*)(LDSB + 16384);
    if (lane < 32)
        lscr[(qg * 2 + ws) * 32 + lane] = lw;
    __syncthreads();
    const float pl2 = lscr[(qg * 2 + (ws ^ 1)) * 32 + l31];
    const float myscale = 1.f / (lw + pl2);
    #pragma unroll
    for (int rc = 0; rc < 4; rc++)
        #pragma unroll
        for (int j = 0; j < 4; j++) {
            const float a = lanepull(myscale, rc * 8 + hl * 4 + j);
            o0[rc * 4 + j] *= a;
            o1[rc * 4 + j] *= a;
        }
    __syncthreads();
    float* Oscr = (float*)(LDSB + qg * 8192);
    if (ws == 1) {
        #pragma unroll
        for (int reg = 0; reg < 16; reg++) {
            const int row = (reg & 3) + 8 * (reg >> 2) + 4 * hl;
            Oscr[row * 64 + l31]      = o0[reg];
            Oscr[row * 64 + 32 + l31] = o1[reg];
        }
    }
    __syncthreads();
    if (ws == 0) {
        #pragma unroll
        for (int reg = 0; reg < 16; reg++) {
            const int row = (reg & 3) + 8 * (reg >> 2) + 4 * hl;
            const float v0 = o0[reg] + Oscr[row * 64 + l31];
            const float v1 = o1[reg] + Oscr[row * 64 + 32 + l31];
            const int srow_ = qt * 64 + qg * 32 + row;
            const size_t idx = ((size_t)b * 4096 + srow_) * 512 + h * 64;
            ctx[idx + l31]      = bfbits(v0);
            ctx[idx + 32 + l31] = bfbits(v1);
        }
    }
}

// ---------------------------------------------------------------------------
extern "C" void kernel_launch(void* const* d_in, const int* in_sizes, int n_in,
                              void* d_out, int out_size, void* d_ws, size_t ws_size,
                              hipStream_t stream)
{
    (void)in_sizes; (void)n_in; (void)out_size; (void)ws_size;
    const float* q  = (const float*)d_in[0];
    const float* k  = (const float*)d_in[1];
    const float* v  = (const float*)d_in[2];
    const float* Wq = (const float*)d_in[3];
    const float* bq = (const float*)d_in[4];
    const float* Wk = (const float*)d_in[5];
    const float* bk = (const float*)d_in[6];
    const float* Wv = (const float*)d_in[7];
    const float* bv = (const float*)d_in[8];
    const float* Wo = (const float*)d_in[9];
    const float* bo = (const float*)d_in[10];
    const float* td = (const float*)d_in[11];
    const float* sc = (const float*)d_in[12];

    // d_ws: Qh, Kh, Vt, ctx (8 MB each) + Wbf (2 MB)
    unsigned short* Qh  = (unsigned short*)d_ws;
    unsigned short* Kh  = Qh + (size_t)16 * 4096 * 64;
    unsigned short* Vt  = Kh + (size_t)16 * 4096 * 64;
    unsigned short* ctx = Vt + (size_t)16 * 4096 * 64;
    unsigned short* Wbf = ctx + (size_t)16 * 4096 * 64;

    // tail scratch in d_out (fully overwritten by gemm_out afterwards):
    // Mt 8 slabs of 16*4096 bf16 = 1 MB; SumV/KsL 8*1024 f32 each.
    unsigned short* Mt   = (unsigned short*)d_out;
    float*          SumV = (float*)((char*)d_out + 8 * 16 * 4096 * 2);
    float*          KsL  = SumV + 8 * 1024;

    wconv<<<dim3(512), 256, 0, stream>>>(Wq, Wk, Wv, Wo, Wbf);
    gemm_qkv<<<dim3(768), 256, 0, stream>>>(q, k, v, Wbf, bq, bk, bv, td, sc, Qh, Kh, Vt);
    tail_pre<<<dim3(128), 512, 0, stream>>>(Kh, Vt, td, sc, Mt, SumV, KsL);
    attn_decay<<<dim3(1024), 256, 0, stream>>>(Qh, Kh, Vt, td, sc, Mt, SumV, KsL, ctx);
    gemm_out<<<dim3(512), 256, 0, stream>>>(ctx, Wbf + (size_t)3 * 262144, bo, (float*)d_out);
}

// Round 15
// 113.995 us; speedup vs baseline: 1.3222x; 1.0168x over previous
//
#include <hip/hip_runtime.h>
#include <hip/hip_bf16.h>
#include <stdint.h>

typedef __attribute__((ext_vector_type(8))) __bf16 bf16x8;
typedef __attribute__((ext_vector_type(4))) float f32x4;
typedef __attribute__((ext_vector_type(16))) float f32x16;
typedef __attribute__((ext_vector_type(8))) unsigned short ushort8;
typedef __attribute__((ext_vector_type(4))) unsigned short ushort4v;
typedef __attribute__((ext_vector_type(2))) unsigned int uint2v;
typedef __attribute__((ext_vector_type(4))) unsigned int uint4v;

__device__ __forceinline__ unsigned short bfbits(float x) {
    __bf16 b = (__bf16)x;
    return __builtin_bit_cast(unsigned short, b);
}
__device__ __forceinline__ float bf2f_u(unsigned short u) {
    return __builtin_bit_cast(float, (unsigned int)u << 16);
}

__device__ __forceinline__ f32x4 mfma16(bf16x8 a, bf16x8 b, f32x4 c) {
    return __builtin_amdgcn_mfma_f32_16x16x32_bf16(a, b, c, 0, 0, 0);
}
__device__ __forceinline__ f32x16 mfma32(bf16x8 a, bf16x8 b, f32x16 c) {
    return __builtin_amdgcn_mfma_f32_32x32x16_bf16(a, b, c, 0, 0, 0);
}

__device__ __forceinline__ unsigned int cvtpk(float lo, float hi) {
    unsigned int r;
    asm("v_cvt_pk_bf16_f32 %0, %1, %2" : "=v"(r) : "v"(lo), "v"(hi));
    return r;
}

__device__ __forceinline__ float lanepull(float src, int srcl) {
    return __builtin_bit_cast(float,
        __builtin_amdgcn_ds_bpermute(srcl * 4, __builtin_bit_cast(int, src)));
}

__device__ __forceinline__ void gload16(const void* g, void* l) {
    __builtin_amdgcn_global_load_lds(
        (const __attribute__((address_space(1))) unsigned int*)g,
        (__attribute__((address_space(3))) unsigned int*)l, 16, 0, 0);
}

__device__ __forceinline__ f32x16 zero16() {
    f32x16 r;
    #pragma unroll
    for (int i = 0; i < 16; i++) r[i] = 0.f;
    return r;
}

__device__ __forceinline__ int tail_tiles(float tdh, float scale) {
    float cut = 5.3f + __logf(fmaxf(scale, 1e-20f));
    cut = fmaxf(cut, 0.f);
    tdh = fmaxf(tdh, 1e-8f);
    int kt = (int)ceilf(cut / (tdh * 64.f));
    if (kt < 1) kt = 1;
    if (kt > 64) kt = 64;
    return kt;
}

// ---------------------------------------------------------------------------
// Weight conversion: Wq,Wk,Wv,Wo fp32 -> bf16 slabs (262144 elems each).
// ---------------------------------------------------------------------------
__global__ __launch_bounds__(256) void wconv(
    const float* __restrict__ Wq, const float* __restrict__ Wk,
    const float* __restrict__ Wv, const float* __restrict__ Wo,
    unsigned short* __restrict__ Wbf)
{
    const int t    = blockIdx.x * 256 + threadIdx.x;
    const int slab = t >> 15;
    const int off8 = t & 32767;
    const float* src = (slab == 0) ? Wq : (slab == 1) ? Wk : (slab == 2) ? Wv : Wo;
    float4 a = ((const float4*)(src + off8 * 8))[0];
    float4 b = ((const float4*)(src + off8 * 8))[1];
    uint4v pk = { cvtpk(a.x, a.y), cvtpk(a.z, a.w), cvtpk(b.x, b.y), cvtpk(b.z, b.w) };
    *(uint4v*)(Wbf + (size_t)slab * 262144 + off8 * 8) = pk;
}

// ---------------------------------------------------------------------------
// Merged Q/K/V projection GEMM v7: R8's 128x128 geometry + counted-vmcnt
// pipeline (T3/T4). 3 rotating 16KB A-bufs, depth-2 prefetch; per iter:
// vmcnt(8) [A(t+1)x4 + B(t+1)x4 stay in flight] -> raw s_barrier ->
// sched_barrier -> issue A/B(t+2) -> frag-read buf t%3 -> MFMA.
// Own-wave LDS writes drain before the barrier => cross-wave reads safe;
// WAR on buf (t+2)%3 is barrier-ordered. 768 blocks XCD-swizzled, 16 iters.
// ---------------------------------------------------------------------------
__global__ __launch_bounds__(256) void gemm_qkv(
    const float* __restrict__ q, const float* __restrict__ k, const float* __restrict__ v,
    const unsigned short* __restrict__ Wbf,
    const float* __restrict__ bq, const float* __restrict__ bk, const float* __restrict__ bv,
    const float* __restrict__ td, const float* __restrict__ sc,
    unsigned short* __restrict__ Qh, unsigned short* __restrict__ Kh,
    unsigned short* __restrict__ Vt)
{
    __shared__ __align__(16) char ALDS[3][16384];

    const int id  = blockIdx.x;
    const int nid = (id & 7) * 96 + (id >> 3);
    const int z   = nid >> 8;
    const int rem = nid & 255;
    const int bm  = rem >> 2;
    const int bn  = rem & 3;

    const float* A0   = (z == 0) ? q  : (z == 1) ? k  : v;
    const float* bias = (z == 0) ? bq : (z == 1) ? bk : bv;

    const int tid  = threadIdx.x;
    const int lane = tid & 63;
    const int w    = tid >> 6;
    const int wm   = w >> 1, wn = w & 1;
    const int l15  = lane & 15;
    const int g    = lane >> 4;

    const int lr  = lane >> 3;
    const int lc  = ((lane & 7) * 16) ^ (lr << 4);
    const char* asrc[4];
    #pragma unroll
    for (int j = 0; j < 4; j++)
        asrc[j] = (const char*)A0 + (size_t)(bm * 128 + w * 32 + j * 8 + lr) * 2048 + lc;
    int adst[4];
    #pragma unroll
    for (int j = 0; j < 4; j++) adst[j] = w * 4096 + j * 1024;

    const unsigned short* Bp[4];
    #pragma unroll
    for (int n = 0; n < 4; n++)
        Bp[n] = Wbf + (size_t)z * 262144
              + (size_t)(bn * 128 + wn * 64 + n * 16 + l15) * 512 + g * 8;

    f32x4 acc[4][4];
    #pragma unroll
    for (int m = 0; m < 4; m++)
        #pragma unroll
        for (int n = 0; n < 4; n++)
            acc[m][n] = (f32x4){0.f, 0.f, 0.f, 0.f};

    const int arow = l15;
    const int asw  = (arow & 7) << 4;

    bf16x8 B0[4], B1[4], B2[4];

    // prologue: tiles 0 and 1 in flight (8 gload16 + 8 B-loads)
    #pragma unroll
    for (int j = 0; j < 4; j++) gload16(asrc[j], ALDS[0] + adst[j]);
    #pragma unroll
    for (int n = 0; n < 4; n++) B0[n] = *(const bf16x8*)Bp[n];
    #pragma unroll
    for (int j = 0; j < 4; j++) gload16(asrc[j] + 128, ALDS[1] + adst[j]);
    #pragma unroll
    for (int n = 0; n < 4; n++) B1[n] = *(const bf16x8*)(Bp[n] + 32);

#define QKV_ITER(KK, BC, BN)                                                       \
    {                                                                              \
        if ((KK) == 15) { asm volatile("s_waitcnt vmcnt(0)" ::: "memory"); }       \
        else            { asm volatile("s_waitcnt vmcnt(8)" ::: "memory"); }       \
        __builtin_amdgcn_s_barrier();                                              \
        __builtin_amdgcn_sched_barrier(0);                                         \
        if ((KK) + 2 < 16) {                                                       \
            _Pragma("unroll")                                                      \
            for (int j = 0; j < 4; j++)                                            \
                gload16(asrc[j] + (size_t)((KK) + 2) * 128,                        \
                        ALDS[((KK) + 2) % 3] + adst[j]);                           \
            _Pragma("unroll")                                                      \
            for (int n = 0; n < 4; n++)                                            \
                BN[n] = *(const bf16x8*)(Bp[n] + (size_t)((KK) + 2) * 32);         \
        }                                                                          \
        bf16x8 af[4];                                                              \
        _Pragma("unroll")                                                          \
        for (int m = 0; m < 4; m++) {                                              \
            const char* base = ALDS[(KK) % 3] + (wm * 64 + m * 16 + arow) * 128;   \
            f32x4 v0 = *(const f32x4*)(base + ((g * 32) ^ asw));                   \
            f32x4 v1 = *(const f32x4*)(base + (((g * 32) | 16) ^ asw));            \
            uint4v pk = { cvtpk(v0.x, v0.y), cvtpk(v0.z, v0.w),                    \
                          cvtpk(v1.x, v1.y), cvtpk(v1.z, v1.w) };                  \
            af[m] = __builtin_bit_cast(bf16x8, pk);                                \
        }                                                                          \
        __builtin_amdgcn_s_setprio(1);                                             \
        _Pragma("unroll")                                                          \
        for (int m = 0; m < 4; m++)                                                \
            _Pragma("unroll")                                                      \
            for (int n = 0; n < 4; n++)                                            \
                acc[m][n] = mfma16(af[m], BC[n], acc[m][n]);                       \
        __builtin_amdgcn_s_setprio(0);                                             \
    }

    QKV_ITER(0,  B0, B2)  QKV_ITER(1,  B1, B0)  QKV_ITER(2,  B2, B1)
    QKV_ITER(3,  B0, B2)  QKV_ITER(4,  B1, B0)  QKV_ITER(5,  B2, B1)
    QKV_ITER(6,  B0, B2)  QKV_ITER(7,  B1, B0)  QKV_ITER(8,  B2, B1)
    QKV_ITER(9,  B0, B2)  QKV_ITER(10, B1, B0)  QKV_ITER(11, B2, B1)
    QKV_ITER(12, B0, B2)  QKV_ITER(13, B1, B0)  QKV_ITER(14, B2, B1)
    QKV_ITER(15, B0, B2)
#undef QKV_ITER

    const float coefL = sc[0] * 0.125f * 1.44269504f;

    #pragma unroll
    for (int m = 0; m < 4; m++) {
        const int grow0 = bm * 128 + wm * 64 + m * 16 + (g << 2);
        #pragma unroll
        for (int n = 0; n < 4; n++) {
            const int gcol = bn * 128 + wn * 64 + n * 16 + l15;
            const float bv2 = bias[gcol];
            f32x4 c = acc[m][n];
            const int b = grow0 >> 12, s0 = grow0 & 4095;
            const int h = gcol >> 6, dk = gcol & 63;
            if (z == 0) {
                const size_t base = ((size_t)(b * 8 + h) * 4096 + s0) * 64 + dk;
                #pragma unroll
                for (int r = 0; r < 4; r++)
                    Qh[base + (size_t)r * 64] = bfbits((c[r] + bv2) * coefL);
            } else if (z == 1) {
                const float tdh = td[h];
                const size_t base = ((size_t)(b * 8 + h) * 4096 + s0) * 64 + dk;
                #pragma unroll
                for (int r = 0; r < 4; r++)
                    Kh[base + (size_t)r * 64] = bfbits((c[r] + bv2) * __expf(-tdh * (float)(s0 + r)));
            } else {
                ushort4v pk = { bfbits(c[0] + bv2), bfbits(c[1] + bv2),
                                bfbits(c[2] + bv2), bfbits(c[3] + bv2) };
                *(ushort4v*)&Vt[((size_t)(b * 8 + h) * 64 + dk) * 4096 + s0] = pk;
            }
        }
    }
}

// ---------------------------------------------------------------------------
// Output projection GEMM v3 (exact R8/R14).
// ---------------------------------------------------------------------------
__global__ __launch_bounds__(256) void gemm_out(
    const unsigned short* __restrict__ Actx, const unsigned short* __restrict__ Wob,
    const float* __restrict__ bias, float* __restrict__ Out)
{
    __shared__ __align__(16) char ALDS[2][16384];

    const int id  = blockIdx.x;
    const int nid = (id & 7) * 64 + (id >> 3);
    const int bm  = nid >> 3;
    const int bn  = nid & 7;

    const int tid  = threadIdx.x;
    const int lane = tid & 63;
    const int w    = tid >> 6;
    const int wm   = w >> 1, wn = w & 1;
    const int l15  = lane & 15;
    const int g    = lane >> 4;

    const int lr  = lane >> 3;
    const int lc  = ((lane & 7) * 16) ^ (lr << 4);
    const char* asrc[4];
    #pragma unroll
    for (int j = 0; j < 4; j++)
        asrc[j] = (const char*)Actx + (size_t)(bm * 128 + w * 32 + j * 8 + lr) * 1024 + lc;
    int adst[4];
    #pragma unroll
    for (int j = 0; j < 4; j++) adst[j] = w * 4096 + j * 1024;

    const unsigned short* Bp[2];
    #pragma unroll
    for (int n = 0; n < 2; n++)
        Bp[n] = Wob + (size_t)(bn * 64 + wn * 32 + n * 16 + l15) * 512 + g * 8;

    f32x4 acc[4][2];
    #pragma unroll
    for (int m = 0; m < 4; m++)
        #pragma unroll
        for (int n = 0; n < 2; n++)
            acc[m][n] = (f32x4){0.f, 0.f, 0.f, 0.f};

    const int arow = l15;
    const int asw  = (arow & 7) << 4;

    #pragma unroll
    for (int j = 0; j < 4; j++) gload16(asrc[j], ALDS[0] + adst[j]);
    bf16x8 BA[2][2], BB[2][2];
    #pragma unroll
    for (int n = 0; n < 2; n++) {
        BA[n][0] = *(const bf16x8*)Bp[n];
        BA[n][1] = *(const bf16x8*)(Bp[n] + 32);
    }

#define OUT_ITER(CUR, KK, BC, BN)                                                  \
    {                                                                              \
        asm volatile("s_waitcnt vmcnt(0)" ::: "memory");                           \
        __syncthreads();                                                           \
        if ((KK) < 7) {                                                            \
            _Pragma("unroll")                                                      \
            for (int j = 0; j < 4; j++)                                            \
                gload16(asrc[j] + (size_t)((KK) + 1) * 128,                        \
                        ALDS[(CUR) ^ 1] + adst[j]);                                \
            _Pragma("unroll")                                                      \
            for (int n = 0; n < 2; n++) {                                          \
                BN[n][0] = *(const bf16x8*)(Bp[n] + (size_t)((KK) + 1) * 64);      \
                BN[n][1] = *(const bf16x8*)(Bp[n] + (size_t)((KK) + 1) * 64 + 32); \
            }                                                                      \
        }                                                                          \
        bf16x8 af[4][2];                                                           \
        _Pragma("unroll")                                                          \
        for (int m = 0; m < 4; m++) {                                              \
            const char* base = ALDS[CUR] + (wm * 64 + m * 16 + arow) * 128;        \
            af[m][0] = *(const bf16x8*)(base + ((g * 16) ^ asw));                  \
            af[m][1] = *(const bf16x8*)(base + ((64 + g * 16) ^ asw));             \
        }                                                                          \
        __builtin_amdgcn_s_setprio(1);                                             \
        _Pragma("unroll")                                                          \
        for (int m = 0; m < 4; m++)                                                \
            _Pragma("unroll")                                                      \
            for (int n = 0; n < 2; n++) {                                          \
                acc[m][n] = mfma16(af[m][0], BC[n][0], acc[m][n]);                 \
                acc[m][n] = mfma16(af[m][1], BC[n][1], acc[m][n]);                 \
            }                                                                      \
        __builtin_amdgcn_s_setprio(0);                                             \
    }

    #pragma unroll 1
    for (int t = 0; t < 4; ++t) {
        OUT_ITER(0, 2 * t, BA, BB)
        OUT_ITER(1, 2 * t + 1, BB, BA)
    }
#undef OUT_ITER

    #pragma unroll
    for (int m = 0; m < 4; m++) {
        const int grow0 = bm * 128 + wm * 64 + m * 16 + (g << 2);
        #pragma unroll
        for (int n = 0; n < 2; n++) {
            const int gcol = bn * 64 + wn * 32 + n * 16 + l15;
            const float bv2 = bias[gcol];
            f32x4 c = acc[m][n];
            #pragma unroll
            for (int r = 0; r < 4; r++)
                Out[(size_t)(grow0 + r) * 512 + gcol] = c[r] + bv2;
        }
    }
}

// ---------------------------------------------------------------------------
// Tail precompute v3 (exact R14): 128 blocks = 16 bh x 8 k-parts.
// ---------------------------------------------------------------------------
__global__ __launch_bounds__(512) void tail_pre(
    const unsigned short* __restrict__ Kh, const unsigned short* __restrict__ Vt,
    const float* __restrict__ td, const float* __restrict__ sc,
    unsigned short* __restrict__ Mt, float* __restrict__ SumV, float* __restrict__ KsL)
{
    __shared__ __align__(16) char KLDS[2][8192];
    __shared__ float redM[4][32][32];
    __shared__ float redv[64];
    __shared__ float redk[64];

    const int blk  = blockIdx.x;
    const int bh   = blk >> 3;
    const int part = blk & 7;
    const int h    = bh & 7;
    const int tid  = threadIdx.x;
    const int w    = tid >> 6;
    const int lane = tid & 63;
    const int l31  = lane & 31, hl = lane >> 5;
    const int d2q  = w & 1, d1q = (w >> 1) & 1, ksub = w >> 2;

    const int KT   = tail_tiles(td[h], sc[0]);
    const int K0   = KT * 64;
    const int nk   = 4096 - K0;
    const int q64  = nk >> 6;
    const int qb   = q64 >> 3, qr = q64 & 7;
    const int nch  = qb + (part < qr ? 1 : 0);
    const int ch0  = part * qb + (part < qr ? part : qr);
    const int kbeg = K0 + ch0 * 64;

    const int lr = lane >> 3;
    const int r8 = (w * 8 + lr) & 7;
    const char* ksrc = (const char*)Kh + (size_t)(bh * 4096 + kbeg + w * 8 + lr) * 128
                     + (((lane & 7) * 16) ^ (r8 << 4));
    const int kdst = w * 1024;

    const unsigned short* Vp = Vt + (size_t)(bh * 64 + d2q * 32 + l31) * 4096 + kbeg;

    f32x16 macc = zero16();
    float sumv = 0.f, ksum = 0.f;

    if (nch > 0) gload16(ksrc, KLDS[0] + kdst);

    #pragma unroll 1
    for (int ch = 0; ch < nch; ++ch) {
        asm volatile("s_waitcnt vmcnt(0)" ::: "memory");
        __syncthreads();
        if (ch + 1 < nch)
            gload16(ksrc + (size_t)(ch + 1) * 8192, KLDS[(ch + 1) & 1] + kdst);
        const char* kb = KLDS[ch & 1];

        #pragma unroll
        for (int mf = 0; mf < 2; mf++) {
            const int kloc0 = ksub * 32 + mf * 16 + hl * 8;
            ushort8 kbv;
            #pragma unroll
            for (int e = 0; e < 8; e++) {
                const int row = kloc0 + e;
                kbv[e] = *(const unsigned short*)(kb + row * 128
                          + ((d1q * 64 + l31 * 2) ^ ((row & 7) << 4)));
            }
            if (d2q == 0) {
                #pragma unroll
                for (int e = 0; e < 8; e++) ksum += bf2f_u(kbv[e]);
            }
            bf16x8 av = *(const bf16x8*)(Vp + ch * 64 + kloc0);
            if (d1q == 0) {
                ushort8 au = __builtin_bit_cast(ushort8, av);
                #pragma unroll
                for (int e = 0; e < 8; e++) sumv += bf2f_u(au[e]);
            }
            macc = mfma32(av, __builtin_bit_cast(bf16x8, kbv), macc);
        }
    }

    sumv += __shfl_xor(sumv, 32);
    ksum += __shfl_xor(ksum, 32);

    const int quad = d2q * 2 + d1q;
    __syncthreads();
    if (ksub == 0) {
        #pragma unroll
        for (int r = 0; r < 16; r++) {
            const int row = (r & 3) + 8 * (r >> 2) + 4 * hl;
            redM[quad][row][l31] = macc[r];
        }
        if (d1q == 0 && hl == 0) redv[d2q * 32 + l31] = sumv;
        if (d2q == 0 && hl == 0) redk[d1q * 32 + l31] = ksum;
    }
    __syncthreads();
    if (ksub == 1) {
        unsigned short* Mb = Mt + (size_t)part * 16 * 4096 + (size_t)bh * 4096;
        #pragma unroll
        for (int r = 0; r < 16; r++) {
            const int row = (r & 3) + 8 * (r >> 2) + 4 * hl;
            const float mv = (macc[r] + redM[quad][row][l31]) * 0.6931472f;
            Mb[(size_t)(d2q * 32 + row) * 64 + d1q * 32 + l31] = bfbits(mv);
        }
        if (d1q == 0 && hl == 0)
            SumV[part * 1024 + bh * 64 + d2q * 32 + l31] = sumv + redv[d2q * 32 + l31];
        if (d2q == 0 && hl == 0)
            KsL[part * 1024 + bh * 64 + d1q * 32 + l31] = (ksum + redk[d1q * 32 + l31]) * 0.6931472f;
    }
}

// ---------------------------------------------------------------------------
// Flash attention over [0, KT*64) + linearized tail (8 partial slabs).
// (exact R14)
// ---------------------------------------------------------------------------
__global__ __launch_bounds__(256, 4) void attn_decay(
    const unsigned short* __restrict__ Qh, const unsigned short* __restrict__ Kh,
    const unsigned short* __restrict__ Vt, const float* __restrict__ td,
    const float* __restrict__ sc,
    const unsigned short* __restrict__ Mt, const float* __restrict__ SumV,
    const float* __restrict__ KsL, unsigned short* __restrict__ ctx)
{
    __shared__ __align__(16) char LDSB[32768];

    const int tid  = threadIdx.x;
    const int lane = tid & 63;
    const int w    = tid >> 6;
    const int qg   = w >> 1;
    const int ws   = w & 1;
    const int l31  = lane & 31;
    const int hl   = lane >> 5;

    const int i  = blockIdx.x;
    const int bh = ((i & 7) << 1) | ((i >> 9) & 1);
    const int qt = (i >> 3) & 63;
    const int h  = bh & 7;
    const int b  = bh >> 3;

    const int KT = tail_tiles(td[h], sc[0]);
    const int nk = 4096 - KT * 64;

    bf16x8 qf[4];
    {
        const unsigned short* Qp =
            Qh + ((size_t)bh * 4096 + qt * 64 + qg * 32 + l31) * 64 + hl * 8;
        #pragma unroll
        for (int c = 0; c < 4; c++)
            qf[c] = *(const bf16x8*)(Qp + c * 16);
    }

    f32x16 o0 = zero16(), o1 = zero16();
    float lp = 0.f;

    const char* kgp0; const char* kgp1; const char* vgp0; const char* vgp1;
    int ldsoff0, ldsoff1;
    {
        const size_t kbaseB = (size_t)bh * 4096 * 64 * 2;
        const size_t vbaseB = (size_t)bh * 64 * 4096 * 2;
        const int p0 = w * 2048 + lane * 16;
        const int r0 = p0 >> 7, c0 = p0 & 127, sw0 = (r0 & 7) << 4;
        const int p1 = w * 2048 + 1024 + lane * 16;
        const int r1 = p1 >> 7, c1 = p1 & 127, sw1 = (r1 & 7) << 4;
        kgp0 = (const char*)Kh + kbaseB + (size_t)r0 * 128  + (c0 ^ sw0);
        kgp1 = (const char*)Kh + kbaseB + (size_t)r1 * 128  + (c1 ^ sw1);
        vgp0 = (const char*)Vt + vbaseB + (size_t)r0 * 8192 + (c0 ^ sw0);
        vgp1 = (const char*)Vt + vbaseB + (size_t)r1 * 8192 + (c1 ^ sw1);
        ldsoff0 = w * 2048;
        ldsoff1 = w * 2048 + 1024;
    }
    gload16(kgp0, LDSB + ldsoff0);
    gload16(kgp1, LDSB + ldsoff1);
    gload16(vgp0, LDSB + 16384 + ldsoff0);
    gload16(vgp1, LDSB + 16384 + ldsoff1);
    kgp0 += 8192; kgp1 += 8192; vgp0 += 128; vgp1 += 128;

    const int krow = ws * 32 + l31;
    const int ksw  = (krow & 7) << 4;

#define ATTN_TILE(CUR, KT_IDX)                                                    \
    {                                                                             \
        asm volatile("s_waitcnt vmcnt(0)" ::: "memory");                          \
        __syncthreads();                                                          \
        if ((KT_IDX) + 1 < KT) {                                                  \
            gload16(kgp0, LDSB + ((CUR) ^ 1) * 8192 + ldsoff0);                   \
            gload16(kgp1, LDSB + ((CUR) ^ 1) * 8192 + ldsoff1);                   \
            gload16(vgp0, LDSB + 16384 + ((CUR) ^ 1) * 8192 + ldsoff0);           \
            gload16(vgp1, LDSB + 16384 + ((CUR) ^ 1) * 8192 + ldsoff1);           \
            kgp0 += 8192; kgp1 += 8192; vgp0 += 128; vgp1 += 128;                 \
        }                                                                         \
        const char* kb = LDSB + (CUR) * 8192;                                     \
        const char* vb = LDSB + 16384 + (CUR) * 8192;                             \
        f32x16 s = zero16();                                                      \
        __builtin_amdgcn_s_setprio(1);                                            \
        _Pragma("unroll")                                                         \
        for (int c = 0; c < 4; c++) {                                             \
            bf16x8 kf = *(const bf16x8*)(kb + krow * 128 + ((c * 32 + hl * 16) ^ ksw)); \
            s = mfma32(kf, qf[c], s);                                             \
        }                                                                         \
        __builtin_amdgcn_s_setprio(0);                                            \
        float p[16];                                                              \
        _Pragma("unroll")                                                         \
        for (int r = 0; r < 16; r++) {                                            \
            p[r] = __builtin_amdgcn_exp2f(s[r]);                                  \
            lp += p[r];                                                           \
        }                                                                         \
        unsigned int W0 = cvtpk(p[0], p[1]),   W1 = cvtpk(p[2], p[3]);            \
        unsigned int W2 = cvtpk(p[4], p[5]),   W3 = cvtpk(p[6], p[7]);            \
        unsigned int W4 = cvtpk(p[8], p[9]),   W5 = cvtpk(p[10], p[11]);          \
        unsigned int W6 = cvtpk(p[12], p[13]), W7 = cvtpk(p[14], p[15]);          \
        uint2v r02 = __builtin_amdgcn_permlane32_swap(W0, W2, false, false);      \
        uint2v r13 = __builtin_amdgcn_permlane32_swap(W1, W3, false, false);      \
        uint2v r46 = __builtin_amdgcn_permlane32_swap(W4, W6, false, false);      \
        uint2v r57 = __builtin_amdgcn_permlane32_swap(W5, W7, false, false);      \
        bf16x8 pa0 = __builtin_bit_cast(bf16x8, (uint4v){r02.x, r13.x, r02.y, r13.y}); \
        bf16x8 pa1 = __builtin_bit_cast(bf16x8, (uint4v){r46.x, r57.x, r46.y, r57.y}); \
        __builtin_amdgcn_s_setprio(1);                                            \
        {                                                                         \
            const int vr0  = l31;                                                 \
            const int vsw0 = (vr0 & 7) << 4;                                      \
            bf16x8 va = *(const bf16x8*)(vb + vr0 * 128 + ((ws * 64 + hl * 16) ^ vsw0));      \
            bf16x8 vb2 = *(const bf16x8*)(vb + vr0 * 128 + ((ws * 64 + 32 + hl * 16) ^ vsw0));\
            o0 = mfma32(pa0, va, o0);                                             \
            o0 = mfma32(pa1, vb2, o0);                                            \
            const int vr1  = 32 + l31;                                            \
            const int vsw1 = (vr1 & 7) << 4;                                      \
            bf16x8 vc = *(const bf16x8*)(vb + vr1 * 128 + ((ws * 64 + hl * 16) ^ vsw1));      \
            bf16x8 vd = *(const bf16x8*)(vb + vr1 * 128 + ((ws * 64 + 32 + hl * 16) ^ vsw1)); \
            o1 = mfma32(pa0, vc, o1);                                             \
            o1 = mfma32(pa1, vd, o1);                                             \
        }                                                                         \
        __builtin_amdgcn_s_setprio(0);                                            \
    }

    const int KT2 = KT >> 1;
    #pragma unroll 1
    for (int t = 0; t < KT2; ++t) {
        ATTN_TILE(0, 2 * t)
        ATTN_TILE(1, 2 * t + 1)
    }
    if (KT & 1) {
        ATTN_TILE(0, KT - 1)
    }
#undef ATTN_TILE

    if (ws == 0 && nk > 0) {
        float qk = 0.f;
        #pragma unroll
        for (int c = 0; c < 4; c++) {
            ushort8 qb2 = __builtin_bit_cast(ushort8, qf[c]);
            #pragma unroll
            for (int e = 0; e < 8; e++) {
                const int idx = c * 16 + hl * 8 + e;
                float ks = 0.f;
                #pragma unroll
                for (int part = 0; part < 8; part++)
                    ks += KsL[part * 1024 + bh * 64 + idx];
                qk += bf2f_u(qb2[e]) * ks;
            }
        }
        qk += __shfl_xor(qk, 32);
        if (hl == 0) lp += (float)nk + qk;

        #pragma unroll 1
        for (int part = 0; part < 8; part++) {
            const unsigned short* Mb = Mt + (size_t)part * 16 * 4096 + (size_t)bh * 4096;
            #pragma unroll
            for (int c = 0; c < 4; c++) {
                bf16x8 m0 = *(const bf16x8*)(Mb + (size_t)l31 * 64 + c * 16 + hl * 8);
                bf16x8 m1 = *(const bf16x8*)(Mb + (size_t)(32 + l31) * 64 + c * 16 + hl * 8);
                o0 = mfma32(qf[c], m0, o0);
                o1 = mfma32(qf[c], m1, o1);
            }
        }
        float sv0 = 0.f, sv1 = 0.f;
        #pragma unroll
        for (int part = 0; part < 8; part++) {
            sv0 += SumV[part * 1024 + bh * 64 + l31];
            sv1 += SumV[part * 1024 + bh * 64 + 32 + l31];
        }
        #pragma unroll
        for (int r = 0; r < 16; r++) { o0[r] += sv0; o1[r] += sv1; }
    }

    float lw = lp + __shfl_xor(lp, 32);
    __syncthreads();
    float* lscr = (float*)(LDSB + 16384);
    if (lane < 32)
        lscr[(qg * 2 + ws) * 32 + lane] = lw;
    __syncthreads();
    const float pl2 = lscr[(qg * 2 + (ws ^ 1)) * 32 + l31];
    const float myscale = 1.f / (lw + pl2);
    #pragma unroll
    for (int rc = 0; rc < 4; rc++)
        #pragma unroll
        for (int j = 0; j < 4; j++) {
            const float a = lanepull(myscale, rc * 8 + hl * 4 + j);
            o0[rc * 4 + j] *= a;
            o1[rc * 4 + j] *= a;
        }
    __syncthreads();
    float* Oscr = (float*)(LDSB + qg * 8192);
    if (ws == 1) {
        #pragma unroll
        for (int reg = 0; reg < 16; reg++) {
            const int row = (reg & 3) + 8 * (reg >> 2) + 4 * hl;
            Oscr[row * 64 + l31]      = o0[reg];
            Oscr[row * 64 + 32 + l31] = o1[reg];
        }
    }
    __syncthreads();
    if (ws == 0) {
        #pragma unroll
        for (int reg = 0; reg < 16; reg++) {
            const int row = (reg & 3) + 8 * (reg >> 2) + 4 * hl;
            const float v0 = o0[reg] + Oscr[row * 64 + l31];
            const float v1 = o1[reg] + Oscr[row * 64 + 32 + l31];
            const int srow_ = qt * 64 + qg * 32 + row;
            const size_t idx = ((size_t)b * 4096 + srow_) * 512 + h * 64;
            ctx[idx + l31]      = bfbits(v0);
            ctx[idx + 32 + l31] = bfbits(v1);
        }
    }
}

// ---------------------------------------------------------------------------
extern "C" void kernel_launch(void* const* d_in, const int* in_sizes, int n_in,
                              void* d_out, int out_size, void* d_ws, size_t ws_size,
                              hipStream_t stream)
{
    (void)in_sizes; (void)n_in; (void)out_size; (void)ws_size;
    const float* q  = (const float*)d_in[0];
    const float* k  = (const float*)d_in[1];
    const float* v  = (const float*)d_in[2];
    const float* Wq = (const float*)d_in[3];
    const float* bq = (const float*)d_in[4];
    const float* Wk = (const float*)d_in[5];
    const float* bk = (const float*)d_in[6];
    const float* Wv = (const float*)d_in[7];
    const float* bv = (const float*)d_in[8];
    const float* Wo = (const float*)d_in[9];
    const float* bo = (const float*)d_in[10];
    const float* td = (const float*)d_in[11];
    const float* sc = (const float*)d_in[12];

    unsigned short* Qh  = (unsigned short*)d_ws;
    unsigned short* Kh  = Qh + (size_t)16 * 4096 * 64;
    unsigned short* Vt  = Kh + (size_t)16 * 4096 * 64;
    unsigned short* ctx = Vt + (size_t)16 * 4096 * 64;
    unsigned short* Wbf = ctx + (size_t)16 * 4096 * 64;

    unsigned short* Mt   = (unsigned short*)d_out;
    float*          SumV = (float*)((char*)d_out + 8 * 16 * 4096 * 2);
    float*          KsL  = SumV + 8 * 1024;

    wconv<<<dim3(512), 256, 0, stream>>>(Wq, Wk, Wv, Wo, Wbf);
    gemm_qkv<<<dim3(768), 256, 0, stream>>>(q, k, v, Wbf, bq, bk, bv, td, sc, Qh, Kh, Vt);
    tail_pre<<<dim3(128), 512, 0, stream>>>(Kh, Vt, td, sc, Mt, SumV, KsL);
    attn_decay<<<dim3(1024), 256, 0, stream>>>(Qh, Kh, Vt, td, sc, Mt, SumV, KsL, ctx);
    gemm_out<<<dim3(512), 256, 0, stream>>>(ctx, Wbf + (size_t)3 * 262144, bo, (float*)d_out);
}